// Round 1
// baseline (2884.050 us; speedup 1.0000x reference)
//
#include <hip/hip_runtime.h>

#define N_NODES 100000
#define N_EDGES 1600000
#define F_IN    128
#define HID     128
#define F_OUT   64
#define ROWS    32   // nodes per block in fused MLP

// ---------------- degree / norm ----------------

__global__ void k_init_deg(float* __restrict__ deg) {
    int i = blockIdx.x * 256 + threadIdx.x;
    if (i < N_NODES) deg[i] = 1.0f;   // self-loop weight
}

__global__ void k_deg_accum(const int* __restrict__ dst,
                            const float* __restrict__ w,
                            float* __restrict__ deg) {
    int e = blockIdx.x * 256 + threadIdx.x;
    if (e < N_EDGES) atomicAdd(&deg[dst[e]], w[e]);
}

__global__ void k_dinv(const float* __restrict__ deg, float* __restrict__ dinv) {
    int i = blockIdx.x * 256 + threadIdx.x;
    if (i < N_NODES) {
        float d = deg[i];
        dinv[i] = d > 0.0f ? rsqrtf(d) : 0.0f;
    }
}

// ax[i][:] = dinv[i]^2 * x[i][:]   (self-loop contribution)
__global__ void k_init_ax(const float* __restrict__ x,
                          const float* __restrict__ dinv,
                          float* __restrict__ ax) {
    int idx = blockIdx.x * 256 + threadIdx.x;     // over N*32 float4
    if (idx < N_NODES * 32) {
        int i = idx >> 5;
        float di = dinv[i];
        float s = di * di;
        float4 v = ((const float4*)x)[idx];
        v.x *= s; v.y *= s; v.z *= s; v.w *= s;
        ((float4*)ax)[idx] = v;
    }
}

// ax[dst] += dinv[src]*w*dinv[dst] * x[src]   — 32 lanes per edge, float4 each
__global__ void k_scatter(const int* __restrict__ src,
                          const int* __restrict__ dst,
                          const float* __restrict__ w,
                          const float* __restrict__ dinv,
                          const float* __restrict__ x,
                          float* __restrict__ ax) {
    int t = blockIdx.x * 256 + threadIdx.x;
    int e = t >> 5;
    int lane = t & 31;
    if (e < N_EDGES) {
        int s = src[e];
        int d = dst[e];
        float nrm = dinv[s] * w[e] * dinv[d];
        float4 v = ((const float4*)x)[s * 32 + lane];
        float* o = ax + (size_t)d * F_IN + lane * 4;
        atomicAdd(o + 0, nrm * v.x);
        atomicAdd(o + 1, nrm * v.y);
        atomicAdd(o + 2, nrm * v.z);
        atomicAdd(o + 3, nrm * v.w);
    }
}

// ---------------- fused MLP: out = relu(ax@W1 + b1) @ W2 + b2 ----------------

__global__ __launch_bounds__(256) void k_fused_mlp(
        const float* __restrict__ ax,
        const float* __restrict__ W1,
        const float* __restrict__ b1,
        const float* __restrict__ W2,
        const float* __restrict__ b2,
        float* __restrict__ out) {
    __shared__ float tile[ROWS][HID];     // 16 KB: ax rows, reused for relu(agg)
    __shared__ float w2s[HID][F_OUT];     // 32 KB

    const int t = threadIdx.x;
    const int row0 = blockIdx.x * ROWS;

    // stage W2 (8192 floats = 2048 float4)
    for (int i = t; i < HID * F_OUT / 4; i += 256)
        ((float4*)w2s)[i] = ((const float4*)W2)[i];
    // stage ax tile (4096 floats = 1024 float4)
    for (int i = t; i < ROWS * HID / 4; i += 256)
        ((float4*)tile)[i] = ((const float4*)(ax + (size_t)row0 * HID))[i];
    __syncthreads();

    // ---- phase 1: agg[32][128] = tile @ W1 ; 4 rows x 4 cols per thread ----
    const int tc = t & 31;   // col group: cols 4*tc .. 4*tc+3
    const int tr = t >> 5;   // row group: rows 4*tr .. 4*tr+3

    float acc[4][4];
    #pragma unroll
    for (int i = 0; i < 4; ++i)
        #pragma unroll
        for (int j = 0; j < 4; ++j) acc[i][j] = 0.0f;

    #pragma unroll 8
    for (int k = 0; k < HID; ++k) {
        float a0 = tile[4 * tr + 0][k];
        float a1 = tile[4 * tr + 1][k];
        float a2 = tile[4 * tr + 2][k];
        float a3 = tile[4 * tr + 3][k];
        float4 wv = *(const float4*)(W1 + k * HID + tc * 4);  // L2-resident
        acc[0][0] += a0 * wv.x; acc[0][1] += a0 * wv.y; acc[0][2] += a0 * wv.z; acc[0][3] += a0 * wv.w;
        acc[1][0] += a1 * wv.x; acc[1][1] += a1 * wv.y; acc[1][2] += a1 * wv.z; acc[1][3] += a1 * wv.w;
        acc[2][0] += a2 * wv.x; acc[2][1] += a2 * wv.y; acc[2][2] += a2 * wv.z; acc[2][3] += a2 * wv.w;
        acc[3][0] += a3 * wv.x; acc[3][1] += a3 * wv.y; acc[3][2] += a3 * wv.z; acc[3][3] += a3 * wv.w;
    }

    float4 b1v = ((const float4*)b1)[tc];
    __syncthreads();   // everyone done READING tile before we overwrite it

    #pragma unroll
    for (int i = 0; i < 4; ++i) {
        tile[4 * tr + i][4 * tc + 0] = fmaxf(acc[i][0] + b1v.x, 0.0f);
        tile[4 * tr + i][4 * tc + 1] = fmaxf(acc[i][1] + b1v.y, 0.0f);
        tile[4 * tr + i][4 * tc + 2] = fmaxf(acc[i][2] + b1v.z, 0.0f);
        tile[4 * tr + i][4 * tc + 3] = fmaxf(acc[i][3] + b1v.w, 0.0f);
    }
    __syncthreads();

    // ---- phase 2: out[32][64] = tile @ W2 ; 2 rows x 4 cols per thread ----
    const int tc2 = t & 15;  // cols 4*tc2 .. 4*tc2+3
    const int tr2 = t >> 4;  // rows 2*tr2, 2*tr2+1

    float acc2[2][4];
    #pragma unroll
    for (int i = 0; i < 2; ++i)
        #pragma unroll
        for (int j = 0; j < 4; ++j) acc2[i][j] = 0.0f;

    #pragma unroll 8
    for (int k = 0; k < HID; ++k) {
        float a0 = tile[2 * tr2 + 0][k];
        float a1 = tile[2 * tr2 + 1][k];
        float4 wv = *(const float4*)(&w2s[k][4 * tc2]);
        acc2[0][0] += a0 * wv.x; acc2[0][1] += a0 * wv.y; acc2[0][2] += a0 * wv.z; acc2[0][3] += a0 * wv.w;
        acc2[1][0] += a1 * wv.x; acc2[1][1] += a1 * wv.y; acc2[1][2] += a1 * wv.z; acc2[1][3] += a1 * wv.w;
    }

    float4 b2v = ((const float4*)b2)[tc2];
    #pragma unroll
    for (int i = 0; i < 2; ++i) {
        float4 r;
        r.x = acc2[i][0] + b2v.x;
        r.y = acc2[i][1] + b2v.y;
        r.z = acc2[i][2] + b2v.z;
        r.w = acc2[i][3] + b2v.w;
        *(float4*)(out + (size_t)(row0 + 2 * tr2 + i) * F_OUT + 4 * tc2) = r;
    }
}

// ---------------- launch ----------------

extern "C" void kernel_launch(void* const* d_in, const int* in_sizes, int n_in,
                              void* d_out, int out_size, void* d_ws, size_t ws_size,
                              hipStream_t stream) {
    const float* x  = (const float*)d_in[0];
    const int*   ei = (const int*)d_in[1];
    const float* ew = (const float*)d_in[2];
    const float* W1 = (const float*)d_in[3];
    const float* b1 = (const float*)d_in[4];
    const float* W2 = (const float*)d_in[5];
    const float* b2 = (const float*)d_in[6];
    float* out = (float*)d_out;

    const int* src = ei;
    const int* dst = ei + N_EDGES;

    float* deg  = (float*)d_ws;                 // N floats
    float* dinv = deg + N_NODES;                // N floats
    float* ax   = dinv + N_NODES;               // N*128 floats (16B-aligned: 800000 % 16 == 0)

    k_init_deg<<<(N_NODES + 255) / 256, 256, 0, stream>>>(deg);
    k_deg_accum<<<(N_EDGES + 255) / 256, 256, 0, stream>>>(dst, ew, deg);
    k_dinv<<<(N_NODES + 255) / 256, 256, 0, stream>>>(deg, dinv);
    k_init_ax<<<(N_NODES * 32 + 255) / 256, 256, 0, stream>>>(x, dinv, ax);
    k_scatter<<<(N_EDGES * 32 + 255) / 256, 256, 0, stream>>>(src, dst, ew, dinv, x, ax);
    k_fused_mlp<<<N_NODES / ROWS, 256, 0, stream>>>(ax, W1, b1, W2, b2, out);
}

// Round 2
// 614.717 us; speedup vs baseline: 4.6917x; 4.6917x over previous
//
#include <hip/hip_runtime.h>

#define N_NODES 100000
#define N_EDGES 1600000
#define F_IN    128
#define HID     128
#define F_OUT   64
#define ROWS    32    // nodes per block in fused MLP

#define SCAN_T  1024
#define CHUNK   ((N_NODES + SCAN_T - 1) / SCAN_T)   // 98

// ---------------- init: deg=1 (self-loop), counts=0, cursor=0 ----------------

__global__ void k_init(float* __restrict__ deg, int* __restrict__ counts,
                       int* __restrict__ cursor) {
    int i = blockIdx.x * 256 + threadIdx.x;
    if (i < N_NODES) { deg[i] = 1.0f; counts[i] = 0; cursor[i] = 0; }
}

// ---------------- histogram: weighted degree + edge counts per dst ----------------

__global__ void k_hist(const int* __restrict__ dst, const float* __restrict__ w,
                       float* __restrict__ deg, int* __restrict__ counts) {
    int e = blockIdx.x * 256 + threadIdx.x;
    if (e < N_EDGES) {
        int d = dst[e];
        atomicAdd(&deg[d], w[e]);
        atomicAdd(&counts[d], 1);
    }
}

__global__ void k_dinv(const float* __restrict__ deg, float* __restrict__ dinv) {
    int i = blockIdx.x * 256 + threadIdx.x;
    if (i < N_NODES) {
        float d = deg[i];
        dinv[i] = d > 0.0f ? rsqrtf(d) : 0.0f;
    }
}

// ---------------- exclusive scan of counts -> row_ptr (single block) ----------------

__global__ __launch_bounds__(SCAN_T) void k_scan(const int* __restrict__ counts,
                                                 int* __restrict__ row_ptr) {
    __shared__ int sums[SCAN_T];
    const int t = threadIdx.x;
    const int start = t * CHUNK;
    int s = 0;
    for (int i = 0; i < CHUNK; ++i) {
        int idx = start + i;
        if (idx < N_NODES) s += counts[idx];
    }
    sums[t] = s;
    __syncthreads();
    for (int off = 1; off < SCAN_T; off <<= 1) {
        int v = (t >= off) ? sums[t - off] : 0;
        __syncthreads();
        sums[t] += v;
        __syncthreads();
    }
    int run = sums[t] - s;   // exclusive prefix for this chunk
    for (int i = 0; i < CHUNK; ++i) {
        int idx = start + i;
        if (idx < N_NODES) {
            row_ptr[idx] = run;
            run += counts[idx];
        }
    }
    if (t == SCAN_T - 1) row_ptr[N_NODES] = sums[t];
}

// ---------------- reorder edges into CSR segments as {src, norm} pairs ----------------

__global__ void k_reorder(const int* __restrict__ src, const int* __restrict__ dst,
                          const float* __restrict__ w, const float* __restrict__ dinv,
                          const int* __restrict__ row_ptr, int* __restrict__ cursor,
                          int2* __restrict__ pairs) {
    int e = blockIdx.x * 256 + threadIdx.x;
    if (e < N_EDGES) {
        int s = src[e];
        int d = dst[e];
        float nrm = dinv[s] * w[e] * dinv[d];
        int pos = row_ptr[d] + atomicAdd(&cursor[d], 1);
        int2 p;
        p.x = s;
        p.y = __float_as_int(nrm);
        pairs[pos] = p;
    }
}

// ---------------- gather-aggregate: ax[n] = dinv[n]^2*x[n] + sum_e norm*x[src] ----------------

__global__ __launch_bounds__(256) void k_gather(const int2* __restrict__ pairs,
                                                const int* __restrict__ row_ptr,
                                                const float* __restrict__ dinv,
                                                const float* __restrict__ x,
                                                float* __restrict__ ax) {
    int t = blockIdx.x * 256 + threadIdx.x;
    int n = t >> 5;
    int lane = t & 31;
    if (n >= N_NODES) return;

    float di = dinv[n];
    float s2 = di * di;
    float4 acc = ((const float4*)x)[n * 32 + lane];
    acc.x *= s2; acc.y *= s2; acc.z *= s2; acc.w *= s2;

    int beg = row_ptr[n];
    int end = row_ptr[n + 1];
    for (int e = beg; e < end; ++e) {
        int2 p = pairs[e];                       // broadcast across the 32-lane group
        float nrm = __int_as_float(p.y);
        float4 v = ((const float4*)x)[p.x * 32 + lane];   // 512B coalesced gather
        acc.x += nrm * v.x;
        acc.y += nrm * v.y;
        acc.z += nrm * v.z;
        acc.w += nrm * v.w;
    }
    ((float4*)ax)[n * 32 + lane] = acc;
}

// ---------------- fused MLP: out = relu(ax@W1 + b1) @ W2 + b2 ----------------

__global__ __launch_bounds__(256) void k_fused_mlp(
        const float* __restrict__ ax,
        const float* __restrict__ W1,
        const float* __restrict__ b1,
        const float* __restrict__ W2,
        const float* __restrict__ b2,
        float* __restrict__ out) {
    __shared__ float tile[ROWS][HID];     // 16 KB: ax rows, reused for relu(agg)
    __shared__ float w2s[HID][F_OUT];     // 32 KB

    const int t = threadIdx.x;
    const int row0 = blockIdx.x * ROWS;

    for (int i = t; i < HID * F_OUT / 4; i += 256)
        ((float4*)w2s)[i] = ((const float4*)W2)[i];
    for (int i = t; i < ROWS * HID / 4; i += 256)
        ((float4*)tile)[i] = ((const float4*)(ax + (size_t)row0 * HID))[i];
    __syncthreads();

    // ---- phase 1: agg[32][128] = tile @ W1 ; 4 rows x 4 cols per thread ----
    const int tc = t & 31;
    const int tr = t >> 5;

    float acc[4][4];
    #pragma unroll
    for (int i = 0; i < 4; ++i)
        #pragma unroll
        for (int j = 0; j < 4; ++j) acc[i][j] = 0.0f;

    #pragma unroll 8
    for (int k = 0; k < HID; ++k) {
        float a0 = tile[4 * tr + 0][k];
        float a1 = tile[4 * tr + 1][k];
        float a2 = tile[4 * tr + 2][k];
        float a3 = tile[4 * tr + 3][k];
        float4 wv = *(const float4*)(W1 + k * HID + tc * 4);  // L2-resident
        acc[0][0] += a0 * wv.x; acc[0][1] += a0 * wv.y; acc[0][2] += a0 * wv.z; acc[0][3] += a0 * wv.w;
        acc[1][0] += a1 * wv.x; acc[1][1] += a1 * wv.y; acc[1][2] += a1 * wv.z; acc[1][3] += a1 * wv.w;
        acc[2][0] += a2 * wv.x; acc[2][1] += a2 * wv.y; acc[2][2] += a2 * wv.z; acc[2][3] += a2 * wv.w;
        acc[3][0] += a3 * wv.x; acc[3][1] += a3 * wv.y; acc[3][2] += a3 * wv.z; acc[3][3] += a3 * wv.w;
    }

    float4 b1v = ((const float4*)b1)[tc];
    __syncthreads();

    #pragma unroll
    for (int i = 0; i < 4; ++i) {
        tile[4 * tr + i][4 * tc + 0] = fmaxf(acc[i][0] + b1v.x, 0.0f);
        tile[4 * tr + i][4 * tc + 1] = fmaxf(acc[i][1] + b1v.y, 0.0f);
        tile[4 * tr + i][4 * tc + 2] = fmaxf(acc[i][2] + b1v.z, 0.0f);
        tile[4 * tr + i][4 * tc + 3] = fmaxf(acc[i][3] + b1v.w, 0.0f);
    }
    __syncthreads();

    // ---- phase 2: out[32][64] = tile @ W2 ; 2 rows x 4 cols per thread ----
    const int tc2 = t & 15;
    const int tr2 = t >> 4;

    float acc2[2][4];
    #pragma unroll
    for (int i = 0; i < 2; ++i)
        #pragma unroll
        for (int j = 0; j < 4; ++j) acc2[i][j] = 0.0f;

    #pragma unroll 8
    for (int k = 0; k < HID; ++k) {
        float a0 = tile[2 * tr2 + 0][k];
        float a1 = tile[2 * tr2 + 1][k];
        float4 wv = *(const float4*)(&w2s[k][4 * tc2]);
        acc2[0][0] += a0 * wv.x; acc2[0][1] += a0 * wv.y; acc2[0][2] += a0 * wv.z; acc2[0][3] += a0 * wv.w;
        acc2[1][0] += a1 * wv.x; acc2[1][1] += a1 * wv.y; acc2[1][2] += a1 * wv.z; acc2[1][3] += a1 * wv.w;
    }

    float4 b2v = ((const float4*)b2)[tc2];
    #pragma unroll
    for (int i = 0; i < 2; ++i) {
        float4 r;
        r.x = acc2[i][0] + b2v.x;
        r.y = acc2[i][1] + b2v.y;
        r.z = acc2[i][2] + b2v.z;
        r.w = acc2[i][3] + b2v.w;
        *(float4*)(out + (size_t)(row0 + 2 * tr2 + i) * F_OUT + 4 * tc2) = r;
    }
}

// ---------------- launch ----------------

extern "C" void kernel_launch(void* const* d_in, const int* in_sizes, int n_in,
                              void* d_out, int out_size, void* d_ws, size_t ws_size,
                              hipStream_t stream) {
    const float* x  = (const float*)d_in[0];
    const int*   ei = (const int*)d_in[1];
    const float* ew = (const float*)d_in[2];
    const float* W1 = (const float*)d_in[3];
    const float* b1 = (const float*)d_in[4];
    const float* W2 = (const float*)d_in[5];
    const float* b2 = (const float*)d_in[6];
    float* out = (float*)d_out;

    const int* src = ei;
    const int* dst = ei + N_EDGES;

    // workspace layout (all offsets keep 16B alignment where needed)
    float* f       = (float*)d_ws;
    float* deg     = f;                          // N
    float* dinv    = f + N_NODES;                // N
    float* ax      = f + 2 * N_NODES;            // 128*N   (byte off 800000, 16B-aligned)
    int*   counts  = (int*)(f + 130 * N_NODES);  // N
    int*   cursor  = counts + N_NODES;           // N
    int*   row_ptr = cursor + N_NODES;           // N+1 (+1 pad to keep evenness)
    int2*  pairs   = (int2*)(row_ptr + N_NODES + 2);   // E pairs (8B-aligned)

    k_init<<<(N_NODES + 255) / 256, 256, 0, stream>>>(deg, counts, cursor);
    k_hist<<<(N_EDGES + 255) / 256, 256, 0, stream>>>(dst, ew, deg, counts);
    k_dinv<<<(N_NODES + 255) / 256, 256, 0, stream>>>(deg, dinv);
    k_scan<<<1, SCAN_T, 0, stream>>>(counts, row_ptr);
    k_reorder<<<(N_EDGES + 255) / 256, 256, 0, stream>>>(src, dst, ew, dinv,
                                                         row_ptr, cursor, pairs);
    k_gather<<<(N_NODES * 32 + 255) / 256, 256, 0, stream>>>(pairs, row_ptr, dinv, x, ax);
    k_fused_mlp<<<N_NODES / ROWS, 256, 0, stream>>>(ax, W1, b1, W2, b2, out);
}

// Round 3
// 435.154 us; speedup vs baseline: 6.6277x; 1.4126x over previous
//
#include <hip/hip_runtime.h>

#define N_NODES 100000
#define N_EDGES 1600000
#define F_IN    128
#define HID     128
#define F_OUT   64
#define ROWS    32    // nodes per block in fused MLP
#define NBLK    ((N_NODES + 255) / 256)   // 391 scan blocks

// ---------------- init: deg=1 (self-loop), counts=0, cursor=0 ----------------

__global__ void k_init(float* __restrict__ deg, int* __restrict__ counts,
                       int* __restrict__ cursor) {
    int i = blockIdx.x * 256 + threadIdx.x;
    if (i < N_NODES) { deg[i] = 1.0f; counts[i] = 0; cursor[i] = 0; }
}

// ---------------- histogram: weighted degree + edge counts per dst ----------------

__global__ void k_hist(const int* __restrict__ dst, const float* __restrict__ w,
                       float* __restrict__ deg, int* __restrict__ counts) {
    int e = blockIdx.x * 256 + threadIdx.x;
    if (e < N_EDGES) {
        int d = dst[e];
        atomicAdd(&deg[d], w[e]);
        atomicAdd(&counts[d], 1);
    }
}

__global__ void k_dinv(const float* __restrict__ deg, float* __restrict__ dinv) {
    int i = blockIdx.x * 256 + threadIdx.x;
    if (i < N_NODES) {
        float d = deg[i];
        dinv[i] = d > 0.0f ? rsqrtf(d) : 0.0f;
    }
}

// ---------------- hierarchical exclusive scan: counts -> row_ptr ----------------

// stage 1: per-block (256-elem) sums
__global__ void k_scan_part(const int* __restrict__ counts, int* __restrict__ part) {
    int i = blockIdx.x * 256 + threadIdx.x;
    int v = (i < N_NODES) ? counts[i] : 0;
    #pragma unroll
    for (int off = 32; off > 0; off >>= 1) v += __shfl_down(v, off, 64);
    __shared__ int ws[4];
    if ((threadIdx.x & 63) == 0) ws[threadIdx.x >> 6] = v;
    __syncthreads();
    if (threadIdx.x == 0) part[blockIdx.x] = ws[0] + ws[1] + ws[2] + ws[3];
}

// stage 2: single block scans the NBLK partials in-place (-> exclusive offsets)
__global__ __launch_bounds__(512) void k_scan_top(int* __restrict__ part,
                                                  int* __restrict__ row_ptr) {
    __shared__ int s[512];
    int t = threadIdx.x;
    int v = (t < NBLK) ? part[t] : 0;
    s[t] = v;
    __syncthreads();
    for (int off = 1; off < 512; off <<= 1) {
        int u = (t >= off) ? s[t - off] : 0;
        __syncthreads();
        s[t] += u;
        __syncthreads();
    }
    if (t < NBLK) part[t] = s[t] - v;     // exclusive block offset
    if (t == 511) row_ptr[N_NODES] = s[511];
}

// stage 3: per-block local exclusive scan + block offset
__global__ void k_scan_down(const int* __restrict__ counts, const int* __restrict__ part,
                            int* __restrict__ row_ptr) {
    __shared__ int s[256];
    int t = threadIdx.x;
    int i = blockIdx.x * 256 + t;
    int v = (i < N_NODES) ? counts[i] : 0;
    s[t] = v;
    __syncthreads();
    for (int off = 1; off < 256; off <<= 1) {
        int u = (t >= off) ? s[t - off] : 0;
        __syncthreads();
        s[t] += u;
        __syncthreads();
    }
    if (i < N_NODES) row_ptr[i] = part[blockIdx.x] + s[t] - v;
}

// ---------------- reorder edges into CSR segments as {src, norm} pairs ----------------

__global__ void k_reorder(const int* __restrict__ src, const int* __restrict__ dst,
                          const float* __restrict__ w, const float* __restrict__ dinv,
                          const int* __restrict__ row_ptr, int* __restrict__ cursor,
                          int2* __restrict__ pairs) {
    int e = blockIdx.x * 256 + threadIdx.x;
    if (e < N_EDGES) {
        int s = src[e];
        int d = dst[e];
        float nrm = dinv[s] * w[e] * dinv[d];
        int pos = row_ptr[d] + atomicAdd(&cursor[d], 1);
        int2 p;
        p.x = s;
        p.y = __float_as_int(nrm);
        pairs[pos] = p;
    }
}

// ---------------- gather-aggregate: ax[n] = dinv[n]^2*x[n] + sum_e norm*x[src] ----------------

__global__ __launch_bounds__(256) void k_gather(const int2* __restrict__ pairs,
                                                const int* __restrict__ row_ptr,
                                                const float* __restrict__ dinv,
                                                const float* __restrict__ x,
                                                float* __restrict__ ax) {
    int t = blockIdx.x * 256 + threadIdx.x;
    int n = t >> 5;
    int lane = t & 31;
    if (n >= N_NODES) return;

    float di = dinv[n];
    float s2 = di * di;
    float4 acc = ((const float4*)x)[n * 32 + lane];
    acc.x *= s2; acc.y *= s2; acc.z *= s2; acc.w *= s2;

    int beg = row_ptr[n];
    int end = row_ptr[n + 1];
    for (int e = beg; e < end; ++e) {
        int2 p = pairs[e];                       // broadcast across the 32-lane group
        float nrm = __int_as_float(p.y);
        float4 v = ((const float4*)x)[p.x * 32 + lane];   // 512B coalesced gather
        acc.x += nrm * v.x;
        acc.y += nrm * v.y;
        acc.z += nrm * v.z;
        acc.w += nrm * v.w;
    }
    ((float4*)ax)[n * 32 + lane] = acc;
}

// ---------------- fused MLP: out = relu(ax@W1 + b1) @ W2 + b2 ----------------

__global__ __launch_bounds__(256) void k_fused_mlp(
        const float* __restrict__ ax,
        const float* __restrict__ W1,
        const float* __restrict__ b1,
        const float* __restrict__ W2,
        const float* __restrict__ b2,
        float* __restrict__ out) {
    __shared__ float tile[ROWS][HID];     // 16 KB: ax rows, reused for relu(agg)
    __shared__ float w2s[HID][F_OUT];     // 32 KB

    const int t = threadIdx.x;
    const int row0 = blockIdx.x * ROWS;

    for (int i = t; i < HID * F_OUT / 4; i += 256)
        ((float4*)w2s)[i] = ((const float4*)W2)[i];
    for (int i = t; i < ROWS * HID / 4; i += 256)
        ((float4*)tile)[i] = ((const float4*)(ax + (size_t)row0 * HID))[i];
    __syncthreads();

    // ---- phase 1: agg[32][128] = tile @ W1 ; 4 rows x 4 cols per thread ----
    const int tc = t & 31;
    const int tr = t >> 5;

    float acc[4][4];
    #pragma unroll
    for (int i = 0; i < 4; ++i)
        #pragma unroll
        for (int j = 0; j < 4; ++j) acc[i][j] = 0.0f;

    #pragma unroll 8
    for (int k = 0; k < HID; ++k) {
        float a0 = tile[4 * tr + 0][k];
        float a1 = tile[4 * tr + 1][k];
        float a2 = tile[4 * tr + 2][k];
        float a3 = tile[4 * tr + 3][k];
        float4 wv = *(const float4*)(W1 + k * HID + tc * 4);  // L2-resident
        acc[0][0] += a0 * wv.x; acc[0][1] += a0 * wv.y; acc[0][2] += a0 * wv.z; acc[0][3] += a0 * wv.w;
        acc[1][0] += a1 * wv.x; acc[1][1] += a1 * wv.y; acc[1][2] += a1 * wv.z; acc[1][3] += a1 * wv.w;
        acc[2][0] += a2 * wv.x; acc[2][1] += a2 * wv.y; acc[2][2] += a2 * wv.z; acc[2][3] += a2 * wv.w;
        acc[3][0] += a3 * wv.x; acc[3][1] += a3 * wv.y; acc[3][2] += a3 * wv.z; acc[3][3] += a3 * wv.w;
    }

    float4 b1v = ((const float4*)b1)[tc];
    __syncthreads();

    #pragma unroll
    for (int i = 0; i < 4; ++i) {
        tile[4 * tr + i][4 * tc + 0] = fmaxf(acc[i][0] + b1v.x, 0.0f);
        tile[4 * tr + i][4 * tc + 1] = fmaxf(acc[i][1] + b1v.y, 0.0f);
        tile[4 * tr + i][4 * tc + 2] = fmaxf(acc[i][2] + b1v.z, 0.0f);
        tile[4 * tr + i][4 * tc + 3] = fmaxf(acc[i][3] + b1v.w, 0.0f);
    }
    __syncthreads();

    // ---- phase 2: out[32][64] = tile @ W2 ; 2 rows x 4 cols per thread ----
    const int tc2 = t & 15;
    const int tr2 = t >> 4;

    float acc2[2][4];
    #pragma unroll
    for (int i = 0; i < 2; ++i)
        #pragma unroll
        for (int j = 0; j < 4; ++j) acc2[i][j] = 0.0f;

    #pragma unroll 8
    for (int k = 0; k < HID; ++k) {
        float a0 = tile[2 * tr2 + 0][k];
        float a1 = tile[2 * tr2 + 1][k];
        float4 wv = *(const float4*)(&w2s[k][4 * tc2]);
        acc2[0][0] += a0 * wv.x; acc2[0][1] += a0 * wv.y; acc2[0][2] += a0 * wv.z; acc2[0][3] += a0 * wv.w;
        acc2[1][0] += a1 * wv.x; acc2[1][1] += a1 * wv.y; acc2[1][2] += a1 * wv.z; acc2[1][3] += a1 * wv.w;
    }

    float4 b2v = ((const float4*)b2)[tc2];
    #pragma unroll
    for (int i = 0; i < 2; ++i) {
        float4 r;
        r.x = acc2[i][0] + b2v.x;
        r.y = acc2[i][1] + b2v.y;
        r.z = acc2[i][2] + b2v.z;
        r.w = acc2[i][3] + b2v.w;
        *(float4*)(out + (size_t)(row0 + 2 * tr2 + i) * F_OUT + 4 * tc2) = r;
    }
}

// ---------------- launch ----------------

extern "C" void kernel_launch(void* const* d_in, const int* in_sizes, int n_in,
                              void* d_out, int out_size, void* d_ws, size_t ws_size,
                              hipStream_t stream) {
    const float* x  = (const float*)d_in[0];
    const int*   ei = (const int*)d_in[1];
    const float* ew = (const float*)d_in[2];
    const float* W1 = (const float*)d_in[3];
    const float* b1 = (const float*)d_in[4];
    const float* W2 = (const float*)d_in[5];
    const float* b2 = (const float*)d_in[6];
    float* out = (float*)d_out;

    const int* src = ei;
    const int* dst = ei + N_EDGES;

    // workspace layout
    float* f       = (float*)d_ws;
    float* deg     = f;                          // N
    float* dinv    = f + N_NODES;                // N
    float* ax      = f + 2 * N_NODES;            // 128*N   (byte off 800000, 16B-aligned)
    int*   counts  = (int*)(f + 130 * N_NODES);  // N
    int*   cursor  = counts + N_NODES;           // N
    int*   row_ptr = cursor + N_NODES;           // N+1 (+1 pad)
    int2*  pairs   = (int2*)(row_ptr + N_NODES + 2);   // E pairs (8B-aligned)
    int*   part    = (int*)(pairs + N_EDGES);    // NBLK partials

    k_init<<<NBLK, 256, 0, stream>>>(deg, counts, cursor);
    k_hist<<<(N_EDGES + 255) / 256, 256, 0, stream>>>(dst, ew, deg, counts);
    k_dinv<<<NBLK, 256, 0, stream>>>(deg, dinv);
    k_scan_part<<<NBLK, 256, 0, stream>>>(counts, part);
    k_scan_top<<<1, 512, 0, stream>>>(part, row_ptr);
    k_scan_down<<<NBLK, 256, 0, stream>>>(counts, part, row_ptr);
    k_reorder<<<(N_EDGES + 255) / 256, 256, 0, stream>>>(src, dst, ew, dinv,
                                                         row_ptr, cursor, pairs);
    k_gather<<<(N_NODES * 32 + 255) / 256, 256, 0, stream>>>(pairs, row_ptr, dinv, x, ax);
    k_fused_mlp<<<N_NODES / ROWS, 256, 0, stream>>>(ax, W1, b1, W2, b2, out);
}

// Round 4
// 321.537 us; speedup vs baseline: 8.9696x; 1.3534x over previous
//
#include <hip/hip_runtime.h>

#define N_NODES 100000
#define N_EDGES 1600000
#define F_IN    128
#define HID     128
#define F_OUT   64
#define ROWS    32    // nodes per block in fused MLP
#define NBLK    ((N_NODES + 255) / 256)   // 391 scan blocks

// ---------------- zero counts ----------------

__global__ void k_zero(int* __restrict__ counts) {
    int i = blockIdx.x * 256 + threadIdx.x;
    if (i < N_NODES) counts[i] = 0;
}

// ---------------- count + rank: the ONLY atomic kernel ----------------

__global__ void k_count(const int* __restrict__ dst,
                        int* __restrict__ counts,
                        unsigned short* __restrict__ rank) {
    int e = blockIdx.x * 256 + threadIdx.x;
    if (e < N_EDGES) {
        int r = atomicAdd(&counts[dst[e]], 1);
        rank[e] = (unsigned short)r;
    }
}

// ---------------- hierarchical exclusive scan: counts -> row_ptr ----------------

__global__ void k_scan_part(const int* __restrict__ counts, int* __restrict__ part) {
    int i = blockIdx.x * 256 + threadIdx.x;
    int v = (i < N_NODES) ? counts[i] : 0;
    #pragma unroll
    for (int off = 32; off > 0; off >>= 1) v += __shfl_down(v, off, 64);
    __shared__ int ws[4];
    if ((threadIdx.x & 63) == 0) ws[threadIdx.x >> 6] = v;
    __syncthreads();
    if (threadIdx.x == 0) part[blockIdx.x] = ws[0] + ws[1] + ws[2] + ws[3];
}

__global__ __launch_bounds__(512) void k_scan_top(int* __restrict__ part,
                                                  int* __restrict__ row_ptr) {
    __shared__ int s[512];
    int t = threadIdx.x;
    int v = (t < NBLK) ? part[t] : 0;
    s[t] = v;
    __syncthreads();
    for (int off = 1; off < 512; off <<= 1) {
        int u = (t >= off) ? s[t - off] : 0;
        __syncthreads();
        s[t] += u;
        __syncthreads();
    }
    if (t < NBLK) part[t] = s[t] - v;
    if (t == 511) row_ptr[N_NODES] = s[511];
}

__global__ void k_scan_down(const int* __restrict__ counts, const int* __restrict__ part,
                            int* __restrict__ row_ptr) {
    __shared__ int s[256];
    int t = threadIdx.x;
    int i = blockIdx.x * 256 + t;
    int v = (i < N_NODES) ? counts[i] : 0;
    s[t] = v;
    __syncthreads();
    for (int off = 1; off < 256; off <<= 1) {
        int u = (t >= off) ? s[t - off] : 0;
        __syncthreads();
        s[t] += u;
        __syncthreads();
    }
    if (i < N_NODES) row_ptr[i] = part[blockIdx.x] + s[t] - v;
}

// ---------------- build CSR pairs {src, w} — NO atomics ----------------

__global__ void k_build(const int* __restrict__ src, const int* __restrict__ dst,
                        const float* __restrict__ w,
                        const int* __restrict__ row_ptr,
                        const unsigned short* __restrict__ rank,
                        int2* __restrict__ pairs) {
    int e = blockIdx.x * 256 + threadIdx.x;
    if (e < N_EDGES) {
        int d = dst[e];
        int pos = row_ptr[d] + (int)rank[e];
        int2 p;
        p.x = src[e];
        p.y = __float_as_int(w[e]);
        pairs[pos] = p;
    }
}

// ---------------- weighted degree from CSR rows (no atomics) ----------------
// deg[n] = 1 + sum_row w ; dinv[n] = rsqrt(deg)  — 8 lanes per node

__global__ void k_deg(const int2* __restrict__ pairs, const int* __restrict__ row_ptr,
                      float* __restrict__ dinv) {
    int t = blockIdx.x * 256 + threadIdx.x;
    int n = t >> 3;
    int lane = t & 7;
    if (n >= N_NODES) return;
    int beg = row_ptr[n];
    int end = row_ptr[n + 1];
    float s = 0.0f;
    for (int e = beg + lane; e < end; e += 8)
        s += __int_as_float(pairs[e].y);
    s += __shfl_xor(s, 1, 8);
    s += __shfl_xor(s, 2, 8);
    s += __shfl_xor(s, 4, 8);
    if (lane == 0) dinv[n] = rsqrtf(1.0f + s);
}

// ---------------- gather-aggregate ----------------
// ax[n] = dinv[n] * ( dinv[n]*x[n] + sum_e dinv[src]*w * x[src] )

__global__ __launch_bounds__(256) void k_gather(const int2* __restrict__ pairs,
                                                const int* __restrict__ row_ptr,
                                                const float* __restrict__ dinv,
                                                const float* __restrict__ x,
                                                float* __restrict__ ax) {
    int t = blockIdx.x * 256 + threadIdx.x;
    int n = t >> 5;
    int lane = t & 31;
    if (n >= N_NODES) return;

    float dn = dinv[n];
    float4 acc = ((const float4*)x)[n * 32 + lane];
    acc.x *= dn; acc.y *= dn; acc.z *= dn; acc.w *= dn;

    int beg = row_ptr[n];
    int end = row_ptr[n + 1];
    for (int e = beg; e < end; ++e) {
        int2 p = pairs[e];                        // broadcast across 32-lane group
        float nw = dinv[p.x] * __int_as_float(p.y);
        float4 v = ((const float4*)x)[p.x * 32 + lane];   // 512B coalesced gather
        acc.x += nw * v.x;
        acc.y += nw * v.y;
        acc.z += nw * v.z;
        acc.w += nw * v.w;
    }
    acc.x *= dn; acc.y *= dn; acc.z *= dn; acc.w *= dn;
    ((float4*)ax)[n * 32 + lane] = acc;
}

// ---------------- fused MLP: out = relu(ax@W1 + b1) @ W2 + b2 ----------------

__global__ __launch_bounds__(256) void k_fused_mlp(
        const float* __restrict__ ax,
        const float* __restrict__ W1,
        const float* __restrict__ b1,
        const float* __restrict__ W2,
        const float* __restrict__ b2,
        float* __restrict__ out) {
    __shared__ float tile[ROWS][HID];     // 16 KB
    __shared__ float w2s[HID][F_OUT];     // 32 KB

    const int t = threadIdx.x;
    const int row0 = blockIdx.x * ROWS;

    for (int i = t; i < HID * F_OUT / 4; i += 256)
        ((float4*)w2s)[i] = ((const float4*)W2)[i];
    for (int i = t; i < ROWS * HID / 4; i += 256)
        ((float4*)tile)[i] = ((const float4*)(ax + (size_t)row0 * HID))[i];
    __syncthreads();

    const int tc = t & 31;
    const int tr = t >> 5;

    float acc[4][4];
    #pragma unroll
    for (int i = 0; i < 4; ++i)
        #pragma unroll
        for (int j = 0; j < 4; ++j) acc[i][j] = 0.0f;

    #pragma unroll 8
    for (int k = 0; k < HID; ++k) {
        float a0 = tile[4 * tr + 0][k];
        float a1 = tile[4 * tr + 1][k];
        float a2 = tile[4 * tr + 2][k];
        float a3 = tile[4 * tr + 3][k];
        float4 wv = *(const float4*)(W1 + k * HID + tc * 4);
        acc[0][0] += a0 * wv.x; acc[0][1] += a0 * wv.y; acc[0][2] += a0 * wv.z; acc[0][3] += a0 * wv.w;
        acc[1][0] += a1 * wv.x; acc[1][1] += a1 * wv.y; acc[1][2] += a1 * wv.z; acc[1][3] += a1 * wv.w;
        acc[2][0] += a2 * wv.x; acc[2][1] += a2 * wv.y; acc[2][2] += a2 * wv.z; acc[2][3] += a2 * wv.w;
        acc[3][0] += a3 * wv.x; acc[3][1] += a3 * wv.y; acc[3][2] += a3 * wv.z; acc[3][3] += a3 * wv.w;
    }

    float4 b1v = ((const float4*)b1)[tc];
    __syncthreads();

    #pragma unroll
    for (int i = 0; i < 4; ++i) {
        tile[4 * tr + i][4 * tc + 0] = fmaxf(acc[i][0] + b1v.x, 0.0f);
        tile[4 * tr + i][4 * tc + 1] = fmaxf(acc[i][1] + b1v.y, 0.0f);
        tile[4 * tr + i][4 * tc + 2] = fmaxf(acc[i][2] + b1v.z, 0.0f);
        tile[4 * tr + i][4 * tc + 3] = fmaxf(acc[i][3] + b1v.w, 0.0f);
    }
    __syncthreads();

    const int tc2 = t & 15;
    const int tr2 = t >> 4;

    float acc2[2][4];
    #pragma unroll
    for (int i = 0; i < 2; ++i)
        #pragma unroll
        for (int j = 0; j < 4; ++j) acc2[i][j] = 0.0f;

    #pragma unroll 8
    for (int k = 0; k < HID; ++k) {
        float a0 = tile[2 * tr2 + 0][k];
        float a1 = tile[2 * tr2 + 1][k];
        float4 wv = *(const float4*)(&w2s[k][4 * tc2]);
        acc2[0][0] += a0 * wv.x; acc2[0][1] += a0 * wv.y; acc2[0][2] += a0 * wv.z; acc2[0][3] += a0 * wv.w;
        acc2[1][0] += a1 * wv.x; acc2[1][1] += a1 * wv.y; acc2[1][2] += a1 * wv.z; acc2[1][3] += a1 * wv.w;
    }

    float4 b2v = ((const float4*)b2)[tc2];
    #pragma unroll
    for (int i = 0; i < 2; ++i) {
        float4 r;
        r.x = acc2[i][0] + b2v.x;
        r.y = acc2[i][1] + b2v.y;
        r.z = acc2[i][2] + b2v.z;
        r.w = acc2[i][3] + b2v.w;
        *(float4*)(out + (size_t)(row0 + 2 * tr2 + i) * F_OUT + 4 * tc2) = r;
    }
}

// ---------------- launch ----------------

extern "C" void kernel_launch(void* const* d_in, const int* in_sizes, int n_in,
                              void* d_out, int out_size, void* d_ws, size_t ws_size,
                              hipStream_t stream) {
    const float* x  = (const float*)d_in[0];
    const int*   ei = (const int*)d_in[1];
    const float* ew = (const float*)d_in[2];
    const float* W1 = (const float*)d_in[3];
    const float* b1 = (const float*)d_in[4];
    const float* W2 = (const float*)d_in[5];
    const float* b2 = (const float*)d_in[6];
    float* out = (float*)d_out;

    const int* src = ei;
    const int* dst = ei + N_EDGES;

    // workspace layout
    float* f       = (float*)d_ws;
    float* dinv    = f;                            // N floats
    float* ax      = f + N_NODES;                  // 128*N floats (byte off 400000, 16B-aligned)
    int*   ibase   = (int*)(f + 129 * N_NODES);
    int*   counts  = ibase;                        // N
    int*   row_ptr = counts + N_NODES;             // N+2
    int*   part    = row_ptr + N_NODES + 2;        // NBLK (+pad to even)
    int*   pafter  = part + ((NBLK + 2) & ~1);     // even offset -> 8B aligned
    int2*  pairs   = (int2*)pafter;                // E pairs
    unsigned short* rank = (unsigned short*)(pairs + N_EDGES);  // E ushorts

    k_zero<<<NBLK, 256, 0, stream>>>(counts);
    k_count<<<(N_EDGES + 255) / 256, 256, 0, stream>>>(dst, counts, rank);
    k_scan_part<<<NBLK, 256, 0, stream>>>(counts, part);
    k_scan_top<<<1, 512, 0, stream>>>(part, row_ptr);
    k_scan_down<<<NBLK, 256, 0, stream>>>(counts, part, row_ptr);
    k_build<<<(N_EDGES + 255) / 256, 256, 0, stream>>>(src, dst, ew, row_ptr, rank, pairs);
    k_deg<<<(N_NODES * 8 + 255) / 256, 256, 0, stream>>>(pairs, row_ptr, dinv);
    k_gather<<<(N_NODES * 32 + 255) / 256, 256, 0, stream>>>(pairs, row_ptr, dinv, x, ax);
    k_fused_mlp<<<N_NODES / ROWS, 256, 0, stream>>>(ax, W1, b1, W2, b2, out);
}

// Round 5
// 289.822 us; speedup vs baseline: 9.9511x; 1.1094x over previous
//
#include <hip/hip_runtime.h>

#define N_NODES 100000
#define N_EDGES 1600000
#define F_IN    128
#define HID     128
#define F_OUT   64
#define ROWS    32    // nodes per block in fused MLP
#define NBLK    ((N_NODES + 255) / 256)   // 391 scan blocks

// ---------------- bf16 helpers (fp32 -> bf16 RN-even, bf16 -> fp32) ----------------

__device__ __forceinline__ unsigned int bf16rn(float f) {
    unsigned int u = __float_as_uint(f);
    return (u + 0x7fffu + ((u >> 16) & 1u)) >> 16;
}
__device__ __forceinline__ float bf16tof(unsigned short h) {
    return __uint_as_float(((unsigned int)h) << 16);
}

// ---------------- convert x to bf16 (xh) — one streaming pass ----------------

__global__ void k_xbf16(const float* __restrict__ x, unsigned short* __restrict__ xh) {
    int i = blockIdx.x * 256 + threadIdx.x;     // each thread: 8 floats -> 8 bf16
    if (i < N_NODES * 16) {
        float4 a = ((const float4*)x)[2 * i];
        float4 b = ((const float4*)x)[2 * i + 1];
        uint4 r;
        r.x = bf16rn(a.x) | (bf16rn(a.y) << 16);
        r.y = bf16rn(a.z) | (bf16rn(a.w) << 16);
        r.z = bf16rn(b.x) | (bf16rn(b.y) << 16);
        r.w = bf16rn(b.z) | (bf16rn(b.w) << 16);
        ((uint4*)xh)[i] = r;
    }
}

// ---------------- zero counts ----------------

__global__ void k_zero(int* __restrict__ counts) {
    int i = blockIdx.x * 256 + threadIdx.x;
    if (i < N_NODES) counts[i] = 0;
}

// ---------------- count + rank: the ONLY atomic kernel ----------------

__global__ void k_count(const int* __restrict__ dst,
                        int* __restrict__ counts,
                        unsigned short* __restrict__ rank) {
    int e = blockIdx.x * 256 + threadIdx.x;
    if (e < N_EDGES) {
        int r = atomicAdd(&counts[dst[e]], 1);
        rank[e] = (unsigned short)r;
    }
}

// ---------------- hierarchical exclusive scan: counts -> row_ptr ----------------

__global__ void k_scan_part(const int* __restrict__ counts, int* __restrict__ part) {
    int i = blockIdx.x * 256 + threadIdx.x;
    int v = (i < N_NODES) ? counts[i] : 0;
    #pragma unroll
    for (int off = 32; off > 0; off >>= 1) v += __shfl_down(v, off, 64);
    __shared__ int ws[4];
    if ((threadIdx.x & 63) == 0) ws[threadIdx.x >> 6] = v;
    __syncthreads();
    if (threadIdx.x == 0) part[blockIdx.x] = ws[0] + ws[1] + ws[2] + ws[3];
}

__global__ __launch_bounds__(512) void k_scan_top(int* __restrict__ part,
                                                  int* __restrict__ row_ptr) {
    __shared__ int s[512];
    int t = threadIdx.x;
    int v = (t < NBLK) ? part[t] : 0;
    s[t] = v;
    __syncthreads();
    for (int off = 1; off < 512; off <<= 1) {
        int u = (t >= off) ? s[t - off] : 0;
        __syncthreads();
        s[t] += u;
        __syncthreads();
    }
    if (t < NBLK) part[t] = s[t] - v;
    if (t == 511) row_ptr[N_NODES] = s[511];
}

__global__ void k_scan_down(const int* __restrict__ counts, const int* __restrict__ part,
                            int* __restrict__ row_ptr) {
    __shared__ int s[256];
    int t = threadIdx.x;
    int i = blockIdx.x * 256 + t;
    int v = (i < N_NODES) ? counts[i] : 0;
    s[t] = v;
    __syncthreads();
    for (int off = 1; off < 256; off <<= 1) {
        int u = (t >= off) ? s[t - off] : 0;
        __syncthreads();
        s[t] += u;
        __syncthreads();
    }
    if (i < N_NODES) row_ptr[i] = part[blockIdx.x] + s[t] - v;
}

// ---------------- build CSR pairs {src, w} — NO atomics ----------------

__global__ void k_build(const int* __restrict__ src, const int* __restrict__ dst,
                        const float* __restrict__ w,
                        const int* __restrict__ row_ptr,
                        const unsigned short* __restrict__ rank,
                        int2* __restrict__ pairs) {
    int e = blockIdx.x * 256 + threadIdx.x;
    if (e < N_EDGES) {
        int d = dst[e];
        int pos = row_ptr[d] + (int)rank[e];
        int2 p;
        p.x = src[e];
        p.y = __float_as_int(w[e]);
        pairs[pos] = p;
    }
}

// ---------------- weighted degree from CSR rows (no atomics) ----------------

__global__ void k_deg(const int2* __restrict__ pairs, const int* __restrict__ row_ptr,
                      float* __restrict__ dinv) {
    int t = blockIdx.x * 256 + threadIdx.x;
    int n = t >> 3;
    int lane = t & 7;
    if (n >= N_NODES) return;
    int beg = row_ptr[n];
    int end = row_ptr[n + 1];
    float s = 0.0f;
    for (int e = beg + lane; e < end; e += 8)
        s += __int_as_float(pairs[e].y);
    s += __shfl_xor(s, 1, 8);
    s += __shfl_xor(s, 2, 8);
    s += __shfl_xor(s, 4, 8);
    if (lane == 0) dinv[n] = rsqrtf(1.0f + s);
}

// ---------------- gather-aggregate (bf16 payload, fp32 accumulate) ----------------
// ax[n] = dinv[n] * ( dinv[n]*x[n] + sum_e dinv[src]*w * xh[src] )

__global__ __launch_bounds__(256) void k_gather(const int2* __restrict__ pairs,
                                                const int* __restrict__ row_ptr,
                                                const float* __restrict__ dinv,
                                                const float* __restrict__ x,
                                                const unsigned short* __restrict__ xh,
                                                float* __restrict__ ax) {
    int t = blockIdx.x * 256 + threadIdx.x;
    int n = t >> 5;
    int lane = t & 31;
    if (n >= N_NODES) return;

    float dn = dinv[n];
    float4 acc = ((const float4*)x)[n * 32 + lane];   // self term from fp32 x (exact)
    acc.x *= dn; acc.y *= dn; acc.z *= dn; acc.w *= dn;

    const ushort4* xh4 = (const ushort4*)xh;          // 4 bf16 per lane-load (8 B)

    int beg = row_ptr[n];
    int end = row_ptr[n + 1];
    int e = beg;
    // unroll-2: two independent gathers in flight
    for (; e + 1 < end; e += 2) {
        int2 p0 = pairs[e];
        int2 p1 = pairs[e + 1];
        float nw0 = dinv[p0.x] * __int_as_float(p0.y);
        float nw1 = dinv[p1.x] * __int_as_float(p1.y);
        ushort4 v0 = xh4[p0.x * 32 + lane];
        ushort4 v1 = xh4[p1.x * 32 + lane];
        acc.x += nw0 * bf16tof(v0.x);
        acc.y += nw0 * bf16tof(v0.y);
        acc.z += nw0 * bf16tof(v0.z);
        acc.w += nw0 * bf16tof(v0.w);
        acc.x += nw1 * bf16tof(v1.x);
        acc.y += nw1 * bf16tof(v1.y);
        acc.z += nw1 * bf16tof(v1.z);
        acc.w += nw1 * bf16tof(v1.w);
    }
    if (e < end) {
        int2 p = pairs[e];
        float nw = dinv[p.x] * __int_as_float(p.y);
        ushort4 v = xh4[p.x * 32 + lane];
        acc.x += nw * bf16tof(v.x);
        acc.y += nw * bf16tof(v.y);
        acc.z += nw * bf16tof(v.z);
        acc.w += nw * bf16tof(v.w);
    }
    acc.x *= dn; acc.y *= dn; acc.z *= dn; acc.w *= dn;
    ((float4*)ax)[n * 32 + lane] = acc;
}

// ---------------- fused MLP: out = relu(ax@W1 + b1) @ W2 + b2 ----------------

__global__ __launch_bounds__(256) void k_fused_mlp(
        const float* __restrict__ ax,
        const float* __restrict__ W1,
        const float* __restrict__ b1,
        const float* __restrict__ W2,
        const float* __restrict__ b2,
        float* __restrict__ out) {
    __shared__ float tile[ROWS][HID];     // 16 KB
    __shared__ float w2s[HID][F_OUT];     // 32 KB

    const int t = threadIdx.x;
    const int row0 = blockIdx.x * ROWS;

    for (int i = t; i < HID * F_OUT / 4; i += 256)
        ((float4*)w2s)[i] = ((const float4*)W2)[i];
    for (int i = t; i < ROWS * HID / 4; i += 256)
        ((float4*)tile)[i] = ((const float4*)(ax + (size_t)row0 * HID))[i];
    __syncthreads();

    const int tc = t & 31;
    const int tr = t >> 5;

    float acc[4][4];
    #pragma unroll
    for (int i = 0; i < 4; ++i)
        #pragma unroll
        for (int j = 0; j < 4; ++j) acc[i][j] = 0.0f;

    #pragma unroll 8
    for (int k = 0; k < HID; ++k) {
        float a0 = tile[4 * tr + 0][k];
        float a1 = tile[4 * tr + 1][k];
        float a2 = tile[4 * tr + 2][k];
        float a3 = tile[4 * tr + 3][k];
        float4 wv = *(const float4*)(W1 + k * HID + tc * 4);
        acc[0][0] += a0 * wv.x; acc[0][1] += a0 * wv.y; acc[0][2] += a0 * wv.z; acc[0][3] += a0 * wv.w;
        acc[1][0] += a1 * wv.x; acc[1][1] += a1 * wv.y; acc[1][2] += a1 * wv.z; acc[1][3] += a1 * wv.w;
        acc[2][0] += a2 * wv.x; acc[2][1] += a2 * wv.y; acc[2][2] += a2 * wv.z; acc[2][3] += a2 * wv.w;
        acc[3][0] += a3 * wv.x; acc[3][1] += a3 * wv.y; acc[3][2] += a3 * wv.z; acc[3][3] += a3 * wv.w;
    }

    float4 b1v = ((const float4*)b1)[tc];
    __syncthreads();

    #pragma unroll
    for (int i = 0; i < 4; ++i) {
        tile[4 * tr + i][4 * tc + 0] = fmaxf(acc[i][0] + b1v.x, 0.0f);
        tile[4 * tr + i][4 * tc + 1] = fmaxf(acc[i][1] + b1v.y, 0.0f);
        tile[4 * tr + i][4 * tc + 2] = fmaxf(acc[i][2] + b1v.z, 0.0f);
        tile[4 * tr + i][4 * tc + 3] = fmaxf(acc[i][3] + b1v.w, 0.0f);
    }
    __syncthreads();

    const int tc2 = t & 15;
    const int tr2 = t >> 4;

    float acc2[2][4];
    #pragma unroll
    for (int i = 0; i < 2; ++i)
        #pragma unroll
        for (int j = 0; j < 4; ++j) acc2[i][j] = 0.0f;

    #pragma unroll 8
    for (int k = 0; k < HID; ++k) {
        float a0 = tile[2 * tr2 + 0][k];
        float a1 = tile[2 * tr2 + 1][k];
        float4 wv = *(const float4*)(&w2s[k][4 * tc2]);
        acc2[0][0] += a0 * wv.x; acc2[0][1] += a0 * wv.y; acc2[0][2] += a0 * wv.z; acc2[0][3] += a0 * wv.w;
        acc2[1][0] += a1 * wv.x; acc2[1][1] += a1 * wv.y; acc2[1][2] += a1 * wv.z; acc2[1][3] += a1 * wv.w;
    }

    float4 b2v = ((const float4*)b2)[tc2];
    #pragma unroll
    for (int i = 0; i < 2; ++i) {
        float4 r;
        r.x = acc2[i][0] + b2v.x;
        r.y = acc2[i][1] + b2v.y;
        r.z = acc2[i][2] + b2v.z;
        r.w = acc2[i][3] + b2v.w;
        *(float4*)(out + (size_t)(row0 + 2 * tr2 + i) * F_OUT + 4 * tc2) = r;
    }
}

// ---------------- launch ----------------

extern "C" void kernel_launch(void* const* d_in, const int* in_sizes, int n_in,
                              void* d_out, int out_size, void* d_ws, size_t ws_size,
                              hipStream_t stream) {
    const float* x  = (const float*)d_in[0];
    const int*   ei = (const int*)d_in[1];
    const float* ew = (const float*)d_in[2];
    const float* W1 = (const float*)d_in[3];
    const float* b1 = (const float*)d_in[4];
    const float* W2 = (const float*)d_in[5];
    const float* b2 = (const float*)d_in[6];
    float* out = (float*)d_out;

    const int* src = ei;
    const int* dst = ei + N_EDGES;

    // workspace layout
    float* f       = (float*)d_ws;
    float* dinv    = f;                              // N floats
    float* ax      = f + N_NODES;                    // 128*N floats
    unsigned short* xh = (unsigned short*)(f + 129 * N_NODES);  // 128*N bf16 (= 64N floats)
    int*   ibase   = (int*)(f + 193 * N_NODES);
    int*   counts  = ibase;                          // N
    int*   row_ptr = counts + N_NODES;               // N+2
    int*   part    = row_ptr + N_NODES + 2;          // NBLK (+pad to even)
    int*   pafter  = part + ((NBLK + 2) & ~1);       // even -> 8B aligned
    int2*  pairs   = (int2*)pafter;                  // E pairs
    unsigned short* rank = (unsigned short*)(pairs + N_EDGES);  // E ushorts

    k_xbf16<<<(N_NODES * 16 + 255) / 256, 256, 0, stream>>>(x, xh);
    k_zero<<<NBLK, 256, 0, stream>>>(counts);
    k_count<<<(N_EDGES + 255) / 256, 256, 0, stream>>>(dst, counts, rank);
    k_scan_part<<<NBLK, 256, 0, stream>>>(counts, part);
    k_scan_top<<<1, 512, 0, stream>>>(part, row_ptr);
    k_scan_down<<<NBLK, 256, 0, stream>>>(counts, part, row_ptr);
    k_build<<<(N_EDGES + 255) / 256, 256, 0, stream>>>(src, dst, ew, row_ptr, rank, pairs);
    k_deg<<<(N_NODES * 8 + 255) / 256, 256, 0, stream>>>(pairs, row_ptr, dinv);
    k_gather<<<(N_NODES * 32 + 255) / 256, 256, 0, stream>>>(pairs, row_ptr, dinv, x, xh, ax);
    k_fused_mlp<<<N_NODES / ROWS, 256, 0, stream>>>(ax, W1, b1, W2, b2, out);
}

// Round 6
// 251.717 us; speedup vs baseline: 11.4575x; 1.1514x over previous
//
#include <hip/hip_runtime.h>

#define N_NODES 100000
#define N_EDGES 1600000
#define F_IN    128
#define HID     128
#define F_OUT   64
#define NBLK    ((N_NODES + 255) / 256)   // 391 scan blocks

typedef __attribute__((ext_vector_type(8))) short bf16x8;
typedef __attribute__((ext_vector_type(4))) float f32x4;

// ---------------- bf16 helpers ----------------

__device__ __forceinline__ unsigned int bf16rn(float f) {
    unsigned int u = __float_as_uint(f);
    return (u + 0x7fffu + ((u >> 16) & 1u)) >> 16;
}
__device__ __forceinline__ float bf16tof(unsigned short h) {
    return __uint_as_float(((unsigned int)h) << 16);
}

// ---------------- convert x to bf16 (xh) — one streaming pass ----------------

__global__ void k_xbf16(const float* __restrict__ x, unsigned short* __restrict__ xh) {
    int i = blockIdx.x * 256 + threadIdx.x;     // each thread: 8 floats -> 8 bf16
    if (i < N_NODES * 16) {
        float4 a = ((const float4*)x)[2 * i];
        float4 b = ((const float4*)x)[2 * i + 1];
        uint4 r;
        r.x = bf16rn(a.x) | (bf16rn(a.y) << 16);
        r.y = bf16rn(a.z) | (bf16rn(a.w) << 16);
        r.z = bf16rn(b.x) | (bf16rn(b.y) << 16);
        r.w = bf16rn(b.z) | (bf16rn(b.w) << 16);
        ((uint4*)xh)[i] = r;
    }
}

// ---------------- transpose + bf16 weights: w1t[n][k], w2t[n][k] ----------------

__global__ void k_wconv(const float* __restrict__ W1, const float* __restrict__ W2,
                        unsigned short* __restrict__ w1t, unsigned short* __restrict__ w2t) {
    int i = blockIdx.x * 256 + threadIdx.x;
    if (i < HID * F_IN) {                       // 16384
        int n = i >> 7, k = i & 127;
        w1t[i] = (unsigned short)bf16rn(W1[k * HID + n]);
    }
    int j = i - HID * F_IN;
    if (j >= 0 && j < F_OUT * HID) {            // 8192
        int n = j >> 7, k = j & 127;
        w2t[j] = (unsigned short)bf16rn(W2[k * F_OUT + n]);
    }
}

// ---------------- zero counts ----------------

__global__ void k_zero(int* __restrict__ counts) {
    int i = blockIdx.x * 256 + threadIdx.x;
    if (i < N_NODES) counts[i] = 0;
}

// ---------------- count + rank: the ONLY atomic kernel ----------------

__global__ void k_count(const int* __restrict__ dst,
                        int* __restrict__ counts,
                        unsigned short* __restrict__ rank) {
    int e = blockIdx.x * 256 + threadIdx.x;
    if (e < N_EDGES) {
        int r = atomicAdd(&counts[dst[e]], 1);
        rank[e] = (unsigned short)r;
    }
}

// ---------------- hierarchical exclusive scan: counts -> row_ptr ----------------

__global__ void k_scan_part(const int* __restrict__ counts, int* __restrict__ part) {
    int i = blockIdx.x * 256 + threadIdx.x;
    int v = (i < N_NODES) ? counts[i] : 0;
    #pragma unroll
    for (int off = 32; off > 0; off >>= 1) v += __shfl_down(v, off, 64);
    __shared__ int ws[4];
    if ((threadIdx.x & 63) == 0) ws[threadIdx.x >> 6] = v;
    __syncthreads();
    if (threadIdx.x == 0) part[blockIdx.x] = ws[0] + ws[1] + ws[2] + ws[3];
}

__global__ __launch_bounds__(512) void k_scan_top(int* __restrict__ part,
                                                  int* __restrict__ row_ptr) {
    __shared__ int s[512];
    int t = threadIdx.x;
    int v = (t < NBLK) ? part[t] : 0;
    s[t] = v;
    __syncthreads();
    for (int off = 1; off < 512; off <<= 1) {
        int u = (t >= off) ? s[t - off] : 0;
        __syncthreads();
        s[t] += u;
        __syncthreads();
    }
    if (t < NBLK) part[t] = s[t] - v;
    if (t == 511) row_ptr[N_NODES] = s[511];
}

__global__ void k_scan_down(const int* __restrict__ counts, const int* __restrict__ part,
                            int* __restrict__ row_ptr) {
    __shared__ int s[256];
    int t = threadIdx.x;
    int i = blockIdx.x * 256 + t;
    int v = (i < N_NODES) ? counts[i] : 0;
    s[t] = v;
    __syncthreads();
    for (int off = 1; off < 256; off <<= 1) {
        int u = (t >= off) ? s[t - off] : 0;
        __syncthreads();
        s[t] += u;
        __syncthreads();
    }
    if (i < N_NODES) row_ptr[i] = part[blockIdx.x] + s[t] - v;
}

// ---------------- build CSR pairs {src, w} — NO atomics ----------------

__global__ void k_build(const int* __restrict__ src, const int* __restrict__ dst,
                        const float* __restrict__ w,
                        const int* __restrict__ row_ptr,
                        const unsigned short* __restrict__ rank,
                        int2* __restrict__ pairs) {
    int e = blockIdx.x * 256 + threadIdx.x;
    if (e < N_EDGES) {
        int d = dst[e];
        int pos = row_ptr[d] + (int)rank[e];
        int2 p;
        p.x = src[e];
        p.y = __float_as_int(w[e]);
        pairs[pos] = p;
    }
}

// ---------------- weighted degree from CSR rows (no atomics) ----------------

__global__ void k_deg(const int2* __restrict__ pairs, const int* __restrict__ row_ptr,
                      float* __restrict__ dinv) {
    int t = blockIdx.x * 256 + threadIdx.x;
    int n = t >> 3;
    int lane = t & 7;
    if (n >= N_NODES) return;
    int beg = row_ptr[n];
    int end = row_ptr[n + 1];
    float s = 0.0f;
    for (int e = beg + lane; e < end; e += 8)
        s += __int_as_float(pairs[e].y);
    s += __shfl_xor(s, 1, 8);
    s += __shfl_xor(s, 2, 8);
    s += __shfl_xor(s, 4, 8);
    if (lane == 0) dinv[n] = rsqrtf(1.0f + s);
}

// ---------------- gather-aggregate (bf16 payload, fp32 accumulate, bf16 out) ----------------
// axh[n] = bf16( dinv[n] * ( dinv[n]*x[n] + sum_e dinv[src]*w * xh[src] ) )

__global__ __launch_bounds__(256) void k_gather(const int2* __restrict__ pairs,
                                                const int* __restrict__ row_ptr,
                                                const float* __restrict__ dinv,
                                                const float* __restrict__ x,
                                                const unsigned short* __restrict__ xh,
                                                unsigned short* __restrict__ axh) {
    int t = blockIdx.x * 256 + threadIdx.x;
    int n = t >> 5;
    int lane = t & 31;
    if (n >= N_NODES) return;

    float dn = dinv[n];
    float4 acc = ((const float4*)x)[n * 32 + lane];   // self term from fp32 x (exact)
    acc.x *= dn; acc.y *= dn; acc.z *= dn; acc.w *= dn;

    const ushort4* xh4 = (const ushort4*)xh;          // 4 bf16 per lane-load (8 B)

    int beg = row_ptr[n];
    int end = row_ptr[n + 1];
    int e = beg;
    for (; e + 1 < end; e += 2) {                     // two independent gathers in flight
        int2 p0 = pairs[e];
        int2 p1 = pairs[e + 1];
        float nw0 = dinv[p0.x] * __int_as_float(p0.y);
        float nw1 = dinv[p1.x] * __int_as_float(p1.y);
        ushort4 v0 = xh4[p0.x * 32 + lane];
        ushort4 v1 = xh4[p1.x * 32 + lane];
        acc.x += nw0 * bf16tof(v0.x);
        acc.y += nw0 * bf16tof(v0.y);
        acc.z += nw0 * bf16tof(v0.z);
        acc.w += nw0 * bf16tof(v0.w);
        acc.x += nw1 * bf16tof(v1.x);
        acc.y += nw1 * bf16tof(v1.y);
        acc.z += nw1 * bf16tof(v1.z);
        acc.w += nw1 * bf16tof(v1.w);
    }
    if (e < end) {
        int2 p = pairs[e];
        float nw = dinv[p.x] * __int_as_float(p.y);
        ushort4 v = xh4[p.x * 32 + lane];
        acc.x += nw * bf16tof(v.x);
        acc.y += nw * bf16tof(v.y);
        acc.z += nw * bf16tof(v.z);
        acc.w += nw * bf16tof(v.w);
    }
    acc.x *= dn; acc.y *= dn; acc.z *= dn; acc.w *= dn;
    uint2 r;
    r.x = bf16rn(acc.x) | (bf16rn(acc.y) << 16);
    r.y = bf16rn(acc.z) | (bf16rn(acc.w) << 16);
    ((uint2*)axh)[n * 32 + lane] = r;
}

// ---------------- MFMA MLP: out = relu(axh@W1 + b1) @ W2 + b2 ----------------
// 4 waves/block, 16 rows/wave. 16x16x32 bf16 MFMA, fp32 accum.
// C/D layout (m89-verified): col = lane&15, row = (lane>>4)*4 + reg.
// A/B frag: row(A)/col(B) = lane&15, k = (lane>>4)*8 + i (contiguous 16B).

__global__ __launch_bounds__(256) void k_mlp(
        const unsigned short* __restrict__ axh,   // [N][128] bf16
        const unsigned short* __restrict__ w1t,   // [128][128] bf16, w1t[n][k]
        const float* __restrict__ b1,
        const unsigned short* __restrict__ w2t,   // [64][128] bf16, w2t[n][k]
        const float* __restrict__ b2,
        float* __restrict__ out) {
    __shared__ unsigned short hbuf[4][16][128];   // per-wave h tile, XOR-swizzled (16 KB)

    const int wid  = threadIdx.x >> 6;
    const int lane = threadIdx.x & 63;
    const int r = lane & 15;
    const int g = lane >> 4;

    const int row0 = (blockIdx.x * 4 + wid) * 16;
    const bool valid = (row0 + 16 <= N_NODES);    // N%16==0: waves all-or-nothing
    const int row0s = valid ? row0 : 0;

    // A fragments for layer 1: a[kt] = axh[row0+r][kt*32 + g*8 .. +7]
    bf16x8 a[4];
    const unsigned short* arow = axh + (size_t)(row0s + r) * HID + g * 8;
    #pragma unroll
    for (int kt = 0; kt < 4; ++kt)
        a[kt] = *(const bf16x8*)(arow + kt * 32);

    const int swr = (r & 7) << 3;

    // ---- layer 1: h[16][128], 8 N-tiles x 4 K-tiles ----
    #pragma unroll
    for (int nt = 0; nt < 8; ++nt) {
        f32x4 acc = {0.f, 0.f, 0.f, 0.f};
        const unsigned short* bcol = w1t + (nt * 16 + r) * HID + g * 8;
        #pragma unroll
        for (int kt = 0; kt < 4; ++kt) {
            bf16x8 b = *(const bf16x8*)(bcol + kt * 32);
            acc = __builtin_amdgcn_mfma_f32_16x16x32_bf16(a[kt], b, acc, 0, 0, 0);
        }
        float bias = b1[nt * 16 + r];
        #pragma unroll
        for (int q = 0; q < 4; ++q) {
            int row = g * 4 + q;
            float v = fmaxf(acc[q] + bias, 0.0f);
            hbuf[wid][row][(nt * 16 + r) ^ ((row & 7) << 3)] = (unsigned short)bf16rn(v);
        }
    }
    __syncthreads();   // all waves reach this (no early returns)

    // A fragments for layer 2 from swizzled LDS (conflict-free ds_read_b128)
    bf16x8 a2[4];
    #pragma unroll
    for (int kt = 0; kt < 4; ++kt)
        a2[kt] = *(const bf16x8*)(&hbuf[wid][r][(kt * 32 + g * 8) ^ swr]);

    // ---- layer 2: out[16][64], 4 N-tiles x 4 K-tiles ----
    #pragma unroll
    for (int nt = 0; nt < 4; ++nt) {
        f32x4 acc = {0.f, 0.f, 0.f, 0.f};
        const unsigned short* bcol = w2t + (nt * 16 + r) * HID + g * 8;
        #pragma unroll
        for (int kt = 0; kt < 4; ++kt) {
            bf16x8 b = *(const bf16x8*)(bcol + kt * 32);
            acc = __builtin_amdgcn_mfma_f32_16x16x32_bf16(a2[kt], b, acc, 0, 0, 0);
        }
        if (valid) {
            float bias = b2[nt * 16 + r];
            #pragma unroll
            for (int q = 0; q < 4; ++q)
                out[(size_t)(row0 + g * 4 + q) * F_OUT + nt * 16 + r] = acc[q] + bias;
        }
    }
}

// ---------------- launch ----------------

extern "C" void kernel_launch(void* const* d_in, const int* in_sizes, int n_in,
                              void* d_out, int out_size, void* d_ws, size_t ws_size,
                              hipStream_t stream) {
    const float* x  = (const float*)d_in[0];
    const int*   ei = (const int*)d_in[1];
    const float* ew = (const float*)d_in[2];
    const float* W1 = (const float*)d_in[3];
    const float* b1 = (const float*)d_in[4];
    const float* W2 = (const float*)d_in[5];
    const float* b2 = (const float*)d_in[6];
    float* out = (float*)d_out;

    const int* src = ei;
    const int* dst = ei + N_EDGES;

    // workspace layout — explicit 16B-aligned carve-out
    char* base = (char*)d_ws;
    auto alloc16 = [&](size_t bytes) { char* p = base; base += (bytes + 15) & ~(size_t)15; return p; };

    float*          dinv    = (float*)         alloc16(N_NODES * 4);
    unsigned short* axh     = (unsigned short*)alloc16((size_t)N_NODES * HID * 2);
    unsigned short* xh      = (unsigned short*)alloc16((size_t)N_NODES * F_IN * 2);
    int*            counts  = (int*)           alloc16(N_NODES * 4);
    int*            row_ptr = (int*)           alloc16((N_NODES + 1) * 4);
    int*            part    = (int*)           alloc16(NBLK * 4);
    int2*           pairs   = (int2*)          alloc16((size_t)N_EDGES * 8);
    unsigned short* rank    = (unsigned short*)alloc16((size_t)N_EDGES * 2);
    unsigned short* w1t     = (unsigned short*)alloc16(HID * F_IN * 2);
    unsigned short* w2t     = (unsigned short*)alloc16(F_OUT * HID * 2);

    k_xbf16<<<(N_NODES * 16 + 255) / 256, 256, 0, stream>>>(x, xh);
    k_wconv<<<(HID * F_IN + F_OUT * HID + 255) / 256, 256, 0, stream>>>(W1, W2, w1t, w2t);
    k_zero<<<NBLK, 256, 0, stream>>>(counts);
    k_count<<<(N_EDGES + 255) / 256, 256, 0, stream>>>(dst, counts, rank);
    k_scan_part<<<NBLK, 256, 0, stream>>>(counts, part);
    k_scan_top<<<1, 512, 0, stream>>>(part, row_ptr);
    k_scan_down<<<NBLK, 256, 0, stream>>>(counts, part, row_ptr);
    k_build<<<(N_EDGES + 255) / 256, 256, 0, stream>>>(src, dst, ew, row_ptr, rank, pairs);
    k_deg<<<(N_NODES * 8 + 255) / 256, 256, 0, stream>>>(pairs, row_ptr, dinv);
    k_gather<<<(N_NODES * 32 + 255) / 256, 256, 0, stream>>>(pairs, row_ptr, dinv, x, xh, axh);
    k_mlp<<<(N_NODES / 16 + 3) / 4, 256, 0, stream>>>(axh, w1t, b1, w2t, b2, out);
}

// Round 7
// 194.432 us; speedup vs baseline: 14.8332x; 1.2946x over previous
//
#include <hip/hip_runtime.h>

#define N_NODES 100000
#define N_EDGES 1600000
#define F_IN    128
#define HID     128
#define F_OUT   64

#define NBUCK   196        // buckets of 512 nodes: dst>>9
#define NCHB    256        // chunk blocks for bucket hist/scatter
#define CHUNK_E (N_EDGES / NCHB)   // 6250 exactly
#define GHN     (NBUCK * NCHB)     // 50176 ghist entries

typedef __attribute__((ext_vector_type(8))) short bf16x8;
typedef __attribute__((ext_vector_type(4))) float f32x4;

// ---------------- bf16 helpers ----------------

__device__ __forceinline__ unsigned int bf16rn(float f) {
    unsigned int u = __float_as_uint(f);
    return (u + 0x7fffu + ((u >> 16) & 1u)) >> 16;
}
__device__ __forceinline__ float bf16tof(unsigned short h) {
    return __uint_as_float(((unsigned int)h) << 16);
}

// ---------------- convert x to bf16 (xh) ----------------

__global__ void k_xbf16(const float* __restrict__ x, unsigned short* __restrict__ xh) {
    int i = blockIdx.x * 256 + threadIdx.x;
    if (i < N_NODES * 16) {
        float4 a = ((const float4*)x)[2 * i];
        float4 b = ((const float4*)x)[2 * i + 1];
        uint4 r;
        r.x = bf16rn(a.x) | (bf16rn(a.y) << 16);
        r.y = bf16rn(a.z) | (bf16rn(a.w) << 16);
        r.z = bf16rn(b.x) | (bf16rn(b.y) << 16);
        r.w = bf16rn(b.z) | (bf16rn(b.w) << 16);
        ((uint4*)xh)[i] = r;
    }
}

// ---------------- transpose + bf16 weights ----------------

__global__ void k_wconv(const float* __restrict__ W1, const float* __restrict__ W2,
                        unsigned short* __restrict__ w1t, unsigned short* __restrict__ w2t) {
    int i = blockIdx.x * 256 + threadIdx.x;
    if (i < HID * F_IN) {
        int n = i >> 7, k = i & 127;
        w1t[i] = (unsigned short)bf16rn(W1[k * HID + n]);
    }
    int j = i - HID * F_IN;
    if (j >= 0 && j < F_OUT * HID) {
        int n = j >> 7, k = j & 127;
        w2t[j] = (unsigned short)bf16rn(W2[k * F_OUT + n]);
    }
}

// ---------------- bucket histogram: LDS atomics only ----------------

__global__ __launch_bounds__(256) void k_bhist(const int* __restrict__ dst,
                                               int* __restrict__ ghist) {
    __shared__ int bins[NBUCK];
    const int t = threadIdx.x;
    const int blk = blockIdx.x;
    for (int j = t; j < NBUCK; j += 256) bins[j] = 0;
    __syncthreads();
    const int base = blk * CHUNK_E;
    for (int i = t; i < CHUNK_E; i += 256)
        atomicAdd(&bins[dst[base + i] >> 9], 1);
    __syncthreads();
    for (int j = t; j < NBUCK; j += 256)
        ghist[j * NCHB + blk] = bins[j];          // bucket-major
}

// ---------------- generalized hierarchical exclusive scan (in-place) ----------------

__global__ void k_scan_part(const int* __restrict__ data, int* __restrict__ part, int n) {
    int i = blockIdx.x * 256 + threadIdx.x;
    int v = (i < n) ? data[i] : 0;
    #pragma unroll
    for (int off = 32; off > 0; off >>= 1) v += __shfl_down(v, off, 64);
    __shared__ int ws[4];
    if ((threadIdx.x & 63) == 0) ws[threadIdx.x >> 6] = v;
    __syncthreads();
    if (threadIdx.x == 0) part[blockIdx.x] = ws[0] + ws[1] + ws[2] + ws[3];
}

__global__ __launch_bounds__(512) void k_scan_top(int* __restrict__ part, int nparts) {
    __shared__ int s[512];
    int t = threadIdx.x;
    int v = (t < nparts) ? part[t] : 0;
    s[t] = v;
    __syncthreads();
    for (int off = 1; off < 512; off <<= 1) {
        int u = (t >= off) ? s[t - off] : 0;
        __syncthreads();
        s[t] += u;
        __syncthreads();
    }
    if (t < nparts) part[t] = s[t] - v;           // exclusive
}

__global__ void k_scan_down(int* __restrict__ data, const int* __restrict__ part, int n) {
    __shared__ int s[256];
    int t = threadIdx.x;
    int i = blockIdx.x * 256 + t;
    int v = (i < n) ? data[i] : 0;
    s[t] = v;
    __syncthreads();
    for (int off = 1; off < 256; off <<= 1) {
        int u = (t >= off) ? s[t - off] : 0;
        __syncthreads();
        s[t] += u;
        __syncthreads();
    }
    if (i < n) data[i] = part[blockIdx.x] + s[t] - v;   // exclusive, in place
}

// ---------------- bucket scatter: LDS cursors, disjoint slot ranges ----------------

__global__ __launch_bounds__(256) void k_bscatter(const int* __restrict__ src,
                                                  const int* __restrict__ dst,
                                                  const float* __restrict__ w,
                                                  const int* __restrict__ ghist,  // scanned
                                                  unsigned short* __restrict__ sd16,
                                                  int2* __restrict__ spw) {
    __shared__ int cur[NBUCK];
    const int t = threadIdx.x;
    const int blk = blockIdx.x;
    for (int j = t; j < NBUCK; j += 256) cur[j] = ghist[j * NCHB + blk];
    __syncthreads();
    const int base = blk * CHUNK_E;
    for (int i = t; i < CHUNK_E; i += 256) {
        int e = base + i;
        int d = dst[e];
        int b = d >> 9;
        int pos = atomicAdd(&cur[b], 1);
        sd16[pos] = (unsigned short)(d & 511);
        int2 p; p.x = src[e]; p.y = __float_as_int(w[e]);
        spw[pos] = p;
    }
}

// ---------------- per-bucket CSR finalize: row_ptr, dinv, pairs (no global atomics) ----------------

__global__ __launch_bounds__(512) void k_csr(const unsigned short* __restrict__ sd16,
                                             const int2* __restrict__ spw,
                                             const int* __restrict__ ghist,   // scanned
                                             int* __restrict__ row_ptr,
                                             float* __restrict__ dinv,
                                             int2* __restrict__ pairs) {
    __shared__ int   scnt[512];
    __shared__ float swsum[512];
    __shared__ int   sexcl[512];
    const int t = threadIdx.x;
    const int b = blockIdx.x;
    const int bstart = ghist[b * NCHB];
    const int bend   = (b == NBUCK - 1) ? N_EDGES : ghist[(b + 1) * NCHB];
    const int ne = bend - bstart;

    scnt[t] = 0; swsum[t] = 0.0f;
    __syncthreads();
    for (int i = t; i < ne; i += 512) {
        int e = bstart + i;
        int dl = (int)sd16[e];
        atomicAdd(&scnt[dl], 1);
        atomicAdd(&swsum[dl], __int_as_float(spw[e].y));
    }
    __syncthreads();

    // exclusive scan of scnt
    sexcl[t] = scnt[t];
    __syncthreads();
    for (int off = 1; off < 512; off <<= 1) {
        int u = (t >= off) ? sexcl[t - off] : 0;
        __syncthreads();
        sexcl[t] += u;
        __syncthreads();
    }
    int excl = sexcl[t] - scnt[t];

    int node = b * 512 + t;
    if (node < N_NODES) {
        row_ptr[node] = bstart + excl;
        dinv[node] = rsqrtf(1.0f + swsum[t]);
    }
    if (b == NBUCK - 1 && t == 0) row_ptr[N_NODES] = N_EDGES;

    sexcl[t] = excl;
    __syncthreads();
    scnt[t] = 0;
    __syncthreads();

    for (int i = t; i < ne; i += 512) {
        int e = bstart + i;
        int dl = (int)sd16[e];
        int r = atomicAdd(&scnt[dl], 1);
        pairs[bstart + sexcl[dl] + r] = spw[e];
    }
}

// ---------------- gather-aggregate (bf16 payload, fp32 accumulate, bf16 out) ----------------

__global__ __launch_bounds__(256) void k_gather(const int2* __restrict__ pairs,
                                                const int* __restrict__ row_ptr,
                                                const float* __restrict__ dinv,
                                                const float* __restrict__ x,
                                                const unsigned short* __restrict__ xh,
                                                unsigned short* __restrict__ axh) {
    int t = blockIdx.x * 256 + threadIdx.x;
    int n = t >> 5;
    int lane = t & 31;
    if (n >= N_NODES) return;

    float dn = dinv[n];
    float4 acc = ((const float4*)x)[n * 32 + lane];   // self term from fp32 x (exact)
    acc.x *= dn; acc.y *= dn; acc.z *= dn; acc.w *= dn;

    const ushort4* xh4 = (const ushort4*)xh;

    int beg = row_ptr[n];
    int end = row_ptr[n + 1];
    int e = beg;
    for (; e + 3 < end; e += 4) {                     // 4 independent gathers in flight
        int2 p0 = pairs[e];
        int2 p1 = pairs[e + 1];
        int2 p2 = pairs[e + 2];
        int2 p3 = pairs[e + 3];
        float nw0 = dinv[p0.x] * __int_as_float(p0.y);
        float nw1 = dinv[p1.x] * __int_as_float(p1.y);
        float nw2 = dinv[p2.x] * __int_as_float(p2.y);
        float nw3 = dinv[p3.x] * __int_as_float(p3.y);
        ushort4 v0 = xh4[p0.x * 32 + lane];
        ushort4 v1 = xh4[p1.x * 32 + lane];
        ushort4 v2 = xh4[p2.x * 32 + lane];
        ushort4 v3 = xh4[p3.x * 32 + lane];
        acc.x += nw0 * bf16tof(v0.x); acc.y += nw0 * bf16tof(v0.y);
        acc.z += nw0 * bf16tof(v0.z); acc.w += nw0 * bf16tof(v0.w);
        acc.x += nw1 * bf16tof(v1.x); acc.y += nw1 * bf16tof(v1.y);
        acc.z += nw1 * bf16tof(v1.z); acc.w += nw1 * bf16tof(v1.w);
        acc.x += nw2 * bf16tof(v2.x); acc.y += nw2 * bf16tof(v2.y);
        acc.z += nw2 * bf16tof(v2.z); acc.w += nw2 * bf16tof(v2.w);
        acc.x += nw3 * bf16tof(v3.x); acc.y += nw3 * bf16tof(v3.y);
        acc.z += nw3 * bf16tof(v3.z); acc.w += nw3 * bf16tof(v3.w);
    }
    for (; e < end; ++e) {
        int2 p = pairs[e];
        float nw = dinv[p.x] * __int_as_float(p.y);
        ushort4 v = xh4[p.x * 32 + lane];
        acc.x += nw * bf16tof(v.x); acc.y += nw * bf16tof(v.y);
        acc.z += nw * bf16tof(v.z); acc.w += nw * bf16tof(v.w);
    }
    acc.x *= dn; acc.y *= dn; acc.z *= dn; acc.w *= dn;
    uint2 r;
    r.x = bf16rn(acc.x) | (bf16rn(acc.y) << 16);
    r.y = bf16rn(acc.z) | (bf16rn(acc.w) << 16);
    ((uint2*)axh)[n * 32 + lane] = r;
}

// ---------------- MFMA MLP: out = relu(axh@W1 + b1) @ W2 + b2 ----------------

__global__ __launch_bounds__(256) void k_mlp(
        const unsigned short* __restrict__ axh,   // [N][128] bf16
        const unsigned short* __restrict__ w1t,   // [128][128] bf16, w1t[n][k]
        const float* __restrict__ b1,
        const unsigned short* __restrict__ w2t,   // [64][128] bf16, w2t[n][k]
        const float* __restrict__ b2,
        float* __restrict__ out) {
    __shared__ unsigned short hbuf[4][16][128];   // per-wave h tile, XOR-swizzled

    const int wid  = threadIdx.x >> 6;
    const int lane = threadIdx.x & 63;
    const int r = lane & 15;
    const int g = lane >> 4;

    const int row0 = (blockIdx.x * 4 + wid) * 16;
    const bool valid = (row0 + 16 <= N_NODES);
    const int row0s = valid ? row0 : 0;

    bf16x8 a[4];
    const unsigned short* arow = axh + (size_t)(row0s + r) * HID + g * 8;
    #pragma unroll
    for (int kt = 0; kt < 4; ++kt)
        a[kt] = *(const bf16x8*)(arow + kt * 32);

    const int swr = (r & 7) << 3;

    #pragma unroll
    for (int nt = 0; nt < 8; ++nt) {
        f32x4 acc = {0.f, 0.f, 0.f, 0.f};
        const unsigned short* bcol = w1t + (nt * 16 + r) * HID + g * 8;
        #pragma unroll
        for (int kt = 0; kt < 4; ++kt) {
            bf16x8 b = *(const bf16x8*)(bcol + kt * 32);
            acc = __builtin_amdgcn_mfma_f32_16x16x32_bf16(a[kt], b, acc, 0, 0, 0);
        }
        float bias = b1[nt * 16 + r];
        #pragma unroll
        for (int q = 0; q < 4; ++q) {
            int row = g * 4 + q;
            float v = fmaxf(acc[q] + bias, 0.0f);
            hbuf[wid][row][(nt * 16 + r) ^ ((row & 7) << 3)] = (unsigned short)bf16rn(v);
        }
    }
    __syncthreads();

    bf16x8 a2[4];
    #pragma unroll
    for (int kt = 0; kt < 4; ++kt)
        a2[kt] = *(const bf16x8*)(&hbuf[wid][r][(kt * 32 + g * 8) ^ swr]);

    #pragma unroll
    for (int nt = 0; nt < 4; ++nt) {
        f32x4 acc = {0.f, 0.f, 0.f, 0.f};
        const unsigned short* bcol = w2t + (nt * 16 + r) * HID + g * 8;
        #pragma unroll
        for (int kt = 0; kt < 4; ++kt) {
            bf16x8 b = *(const bf16x8*)(bcol + kt * 32);
            acc = __builtin_amdgcn_mfma_f32_16x16x32_bf16(a2[kt], b, acc, 0, 0, 0);
        }
        if (valid) {
            float bias = b2[nt * 16 + r];
            #pragma unroll
            for (int q = 0; q < 4; ++q)
                out[(size_t)(row0 + g * 4 + q) * F_OUT + nt * 16 + r] = acc[q] + bias;
        }
    }
}

// ---------------- launch ----------------

extern "C" void kernel_launch(void* const* d_in, const int* in_sizes, int n_in,
                              void* d_out, int out_size, void* d_ws, size_t ws_size,
                              hipStream_t stream) {
    const float* x  = (const float*)d_in[0];
    const int*   ei = (const int*)d_in[1];
    const float* ew = (const float*)d_in[2];
    const float* W1 = (const float*)d_in[3];
    const float* b1 = (const float*)d_in[4];
    const float* W2 = (const float*)d_in[5];
    const float* b2 = (const float*)d_in[6];
    float* out = (float*)d_out;

    const int* src = ei;
    const int* dst = ei + N_EDGES;

    // workspace layout — explicit 16B-aligned carve-out
    char* base = (char*)d_ws;
    auto alloc16 = [&](size_t bytes) { char* p = base; base += (bytes + 15) & ~(size_t)15; return p; };

    float*          dinv    = (float*)         alloc16(N_NODES * 4);
    unsigned short* axh     = (unsigned short*)alloc16((size_t)N_NODES * HID * 2);
    unsigned short* xh      = (unsigned short*)alloc16((size_t)N_NODES * F_IN * 2);
    int*            row_ptr = (int*)           alloc16((N_NODES + 1) * 4);
    int*            ghist   = (int*)           alloc16(GHN * 4);
    int*            part    = (int*)           alloc16(256 * 4);
    int2*           pairs   = (int2*)          alloc16((size_t)N_EDGES * 8);
    int2*           spw     = (int2*)          alloc16((size_t)N_EDGES * 8);
    unsigned short* sd16    = (unsigned short*)alloc16((size_t)N_EDGES * 2);
    unsigned short* w1t     = (unsigned short*)alloc16(HID * F_IN * 2);
    unsigned short* w2t     = (unsigned short*)alloc16(F_OUT * HID * 2);

    const int GH_BLKS = (GHN + 255) / 256;   // 196

    k_xbf16<<<(N_NODES * 16 + 255) / 256, 256, 0, stream>>>(x, xh);
    k_wconv<<<(HID * F_IN + F_OUT * HID + 255) / 256, 256, 0, stream>>>(W1, W2, w1t, w2t);
    k_bhist<<<NCHB, 256, 0, stream>>>(dst, ghist);
    k_scan_part<<<GH_BLKS, 256, 0, stream>>>(ghist, part, GHN);
    k_scan_top<<<1, 512, 0, stream>>>(part, GH_BLKS);
    k_scan_down<<<GH_BLKS, 256, 0, stream>>>(ghist, part, GHN);
    k_bscatter<<<NCHB, 256, 0, stream>>>(src, dst, ew, ghist, sd16, spw);
    k_csr<<<NBUCK, 512, 0, stream>>>(sd16, spw, ghist, row_ptr, dinv, pairs);
    k_gather<<<(N_NODES * 32 + 255) / 256, 256, 0, stream>>>(pairs, row_ptr, dinv, x, xh, axh);
    k_mlp<<<(N_NODES / 16 + 3) / 4, 256, 0, stream>>>(axh, w1t, b1, w2t, b2, out);
}

// Round 8
// 176.232 us; speedup vs baseline: 16.3651x; 1.1033x over previous
//
#include <hip/hip_runtime.h>

#define N_NODES 100000
#define N_EDGES 1600000
#define F_IN    128
#define HID     128
#define F_OUT   64

#define NBUCK   196        // buckets of 512 nodes: dst>>9
#define NCHB    256        // chunk blocks for bucket hist/scatter
#define CHUNK_E (N_EDGES / NCHB)   // 6250 exactly
#define GHN     (NBUCK * NCHB)     // 50176 ghist entries

#define XB_BLKS (N_NODES * 16 / 256)                  // 6250 (exact)
#define WC_BLKS ((HID * F_IN + F_OUT * HID + 255) / 256)  // 96

typedef __attribute__((ext_vector_type(8))) short bf16x8;
typedef __attribute__((ext_vector_type(4))) float f32x4;

// ---------------- bf16 helpers ----------------

__device__ __forceinline__ unsigned int bf16rn(float f) {
    unsigned int u = __float_as_uint(f);
    return (u + 0x7fffu + ((u >> 16) & 1u)) >> 16;
}
__device__ __forceinline__ float bf16tof(unsigned short h) {
    return __uint_as_float(((unsigned int)h) << 16);
}

// ---------------- pre: xh convert + weight transpose + bucket histogram ----------------

__global__ __launch_bounds__(256) void k_pre(
        const float* __restrict__ x, unsigned short* __restrict__ xh,
        const float* __restrict__ W1, const float* __restrict__ W2,
        unsigned short* __restrict__ w1t, unsigned short* __restrict__ w2t,
        const int* __restrict__ dst, int* __restrict__ ghist) {
    __shared__ int bins[NBUCK];
    const int blk = blockIdx.x;
    const int t = threadIdx.x;
    if (blk < XB_BLKS) {
        // x -> bf16, 8 floats per thread
        int i = blk * 256 + t;
        float4 a = ((const float4*)x)[2 * i];
        float4 b = ((const float4*)x)[2 * i + 1];
        uint4 r;
        r.x = bf16rn(a.x) | (bf16rn(a.y) << 16);
        r.y = bf16rn(a.z) | (bf16rn(a.w) << 16);
        r.z = bf16rn(b.x) | (bf16rn(b.y) << 16);
        r.w = bf16rn(b.z) | (bf16rn(b.w) << 16);
        ((uint4*)xh)[i] = r;
    } else if (blk < XB_BLKS + WC_BLKS) {
        // transpose + bf16 weights
        int i = (blk - XB_BLKS) * 256 + t;
        if (i < HID * F_IN) {
            int n = i >> 7, k = i & 127;
            w1t[i] = (unsigned short)bf16rn(W1[k * HID + n]);
        }
        int j = i - HID * F_IN;
        if (j >= 0 && j < F_OUT * HID) {
            int n = j >> 7, k = j & 127;
            w2t[j] = (unsigned short)bf16rn(W2[k * F_OUT + n]);
        }
    } else {
        // bucket histogram: LDS atomics only
        int cb = blk - XB_BLKS - WC_BLKS;
        for (int j = t; j < NBUCK; j += 256) bins[j] = 0;
        __syncthreads();
        const int base = cb * CHUNK_E;
        for (int i = t; i < CHUNK_E; i += 256)
            atomicAdd(&bins[dst[base + i] >> 9], 1);
        __syncthreads();
        for (int j = t; j < NBUCK; j += 256)
            ghist[j * NCHB + cb] = bins[j];       // bucket-major
    }
}

// ---------------- generalized hierarchical exclusive scan (in-place) ----------------

__global__ void k_scan_part(const int* __restrict__ data, int* __restrict__ part, int n) {
    int i = blockIdx.x * 256 + threadIdx.x;
    int v = (i < n) ? data[i] : 0;
    #pragma unroll
    for (int off = 32; off > 0; off >>= 1) v += __shfl_down(v, off, 64);
    __shared__ int ws[4];
    if ((threadIdx.x & 63) == 0) ws[threadIdx.x >> 6] = v;
    __syncthreads();
    if (threadIdx.x == 0) part[blockIdx.x] = ws[0] + ws[1] + ws[2] + ws[3];
}

__global__ __launch_bounds__(512) void k_scan_top(int* __restrict__ part, int nparts) {
    __shared__ int s[512];
    int t = threadIdx.x;
    int v = (t < nparts) ? part[t] : 0;
    s[t] = v;
    __syncthreads();
    for (int off = 1; off < 512; off <<= 1) {
        int u = (t >= off) ? s[t - off] : 0;
        __syncthreads();
        s[t] += u;
        __syncthreads();
    }
    if (t < nparts) part[t] = s[t] - v;           // exclusive
}

__global__ void k_scan_down(int* __restrict__ data, const int* __restrict__ part, int n) {
    __shared__ int s[256];
    int t = threadIdx.x;
    int i = blockIdx.x * 256 + t;
    int v = (i < n) ? data[i] : 0;
    s[t] = v;
    __syncthreads();
    for (int off = 1; off < 256; off <<= 1) {
        int u = (t >= off) ? s[t - off] : 0;
        __syncthreads();
        s[t] += u;
        __syncthreads();
    }
    if (i < n) data[i] = part[blockIdx.x] + s[t] - v;   // exclusive, in place
}

// ---------------- bucket scatter: LDS cursors, dlocal packed into bits 17..25 ----------------

__global__ __launch_bounds__(256) void k_bscatter(const int* __restrict__ src,
                                                  const int* __restrict__ dst,
                                                  const float* __restrict__ w,
                                                  const int* __restrict__ ghist,  // scanned
                                                  int2* __restrict__ spw) {
    __shared__ int cur[NBUCK];
    const int t = threadIdx.x;
    const int blk = blockIdx.x;
    for (int j = t; j < NBUCK; j += 256) cur[j] = ghist[j * NCHB + blk];
    __syncthreads();
    const int base = blk * CHUNK_E;
    for (int i = t; i < CHUNK_E; i += 256) {
        int e = base + i;
        int d = dst[e];
        int b = d >> 9;
        int pos = atomicAdd(&cur[b], 1);
        int2 p;
        p.x = src[e] | ((d & 511) << 17);     // src < 2^17
        p.y = __float_as_int(w[e]);
        spw[pos] = p;
    }
}

// ---------------- per-bucket CSR finalize: row_ptr, dinv, pairs ----------------

__global__ __launch_bounds__(512) void k_csr(const int2* __restrict__ spw,
                                             const int* __restrict__ ghist,   // scanned
                                             int* __restrict__ row_ptr,
                                             float* __restrict__ dinv,
                                             int2* __restrict__ pairs) {
    __shared__ int   scnt[512];
    __shared__ float swsum[512];
    __shared__ int   sexcl[512];
    const int t = threadIdx.x;
    const int b = blockIdx.x;
    const int bstart = ghist[b * NCHB];
    const int bend   = (b == NBUCK - 1) ? N_EDGES : ghist[(b + 1) * NCHB];
    const int ne = bend - bstart;

    scnt[t] = 0; swsum[t] = 0.0f;
    __syncthreads();
    for (int i = t; i < ne; i += 512) {
        int2 pe = spw[bstart + i];
        int dl = pe.x >> 17;
        atomicAdd(&scnt[dl], 1);
        atomicAdd(&swsum[dl], __int_as_float(pe.y));
    }
    __syncthreads();

    // exclusive scan of scnt
    sexcl[t] = scnt[t];
    __syncthreads();
    for (int off = 1; off < 512; off <<= 1) {
        int u = (t >= off) ? sexcl[t - off] : 0;
        __syncthreads();
        sexcl[t] += u;
        __syncthreads();
    }
    int excl = sexcl[t] - scnt[t];

    int node = b * 512 + t;
    if (node < N_NODES) {
        row_ptr[node] = bstart + excl;
        dinv[node] = rsqrtf(1.0f + swsum[t]);
    }
    if (b == NBUCK - 1 && t == 0) row_ptr[N_NODES] = N_EDGES;

    sexcl[t] = excl;
    __syncthreads();
    scnt[t] = 0;
    __syncthreads();

    for (int i = t; i < ne; i += 512) {
        int2 pe = spw[bstart + i];
        int dl = pe.x >> 17;
        int r = atomicAdd(&scnt[dl], 1);
        int2 q;
        q.x = pe.x & 0x1FFFF;
        q.y = pe.y;
        pairs[bstart + sexcl[dl] + r] = q;
    }
}

// ---------------- fused gather + 2-layer MFMA MLP ----------------
// Block = 512 threads = 16 nodes. Phase A: 32 lanes/node gather into LDS tile
// (bf16, XOR-swizzled). Phase B: 8 waves, wave w computes h cols w*16..+15.
// Phase C: waves 0..3 compute out cols w*16..+15.
// MFMA 16x16x32 bf16; A/B frag: row/col = lane&15, k = (lane>>4)*8 + i + kt*32;
// C/D: col = lane&15, row = (lane>>4)*4 + q  (m89-verified).

__global__ __launch_bounds__(512) void k_gmlp(
        const int2* __restrict__ pairs,
        const int* __restrict__ row_ptr,
        const float* __restrict__ dinv,
        const unsigned short* __restrict__ xh,
        const unsigned short* __restrict__ w1t,   // [128][128] bf16, w1t[n][k]
        const float* __restrict__ b1,
        const unsigned short* __restrict__ w2t,   // [64][128] bf16, w2t[n][k]
        const float* __restrict__ b2,
        float* __restrict__ out) {
    __shared__ unsigned short gt[16][128];   // gathered ax tile (swizzled)
    __shared__ unsigned short ht[16][128];   // relu(h) tile (swizzled)

    const int t = threadIdx.x;
    const int row0 = blockIdx.x * 16;

    // ---- phase A: gather ----
    {
        const int grp  = t >> 5;
        const int lane = t & 31;
        const int n = row0 + grp;
        const float dn = dinv[n];
        const ushort4* xh4 = (const ushort4*)xh;

        ushort4 sv = xh4[n * 32 + lane];          // self term (bf16)
        float4 acc;
        acc.x = dn * bf16tof(sv.x);
        acc.y = dn * bf16tof(sv.y);
        acc.z = dn * bf16tof(sv.z);
        acc.w = dn * bf16tof(sv.w);

        int beg = row_ptr[n];
        int end = row_ptr[n + 1];
        int e = beg;
        for (; e + 3 < end; e += 4) {             // 4 independent gathers in flight
            int2 p0 = pairs[e];
            int2 p1 = pairs[e + 1];
            int2 p2 = pairs[e + 2];
            int2 p3 = pairs[e + 3];
            float nw0 = dinv[p0.x] * __int_as_float(p0.y);
            float nw1 = dinv[p1.x] * __int_as_float(p1.y);
            float nw2 = dinv[p2.x] * __int_as_float(p2.y);
            float nw3 = dinv[p3.x] * __int_as_float(p3.y);
            ushort4 v0 = xh4[p0.x * 32 + lane];
            ushort4 v1 = xh4[p1.x * 32 + lane];
            ushort4 v2 = xh4[p2.x * 32 + lane];
            ushort4 v3 = xh4[p3.x * 32 + lane];
            acc.x += nw0 * bf16tof(v0.x); acc.y += nw0 * bf16tof(v0.y);
            acc.z += nw0 * bf16tof(v0.z); acc.w += nw0 * bf16tof(v0.w);
            acc.x += nw1 * bf16tof(v1.x); acc.y += nw1 * bf16tof(v1.y);
            acc.z += nw1 * bf16tof(v1.z); acc.w += nw1 * bf16tof(v1.w);
            acc.x += nw2 * bf16tof(v2.x); acc.y += nw2 * bf16tof(v2.y);
            acc.z += nw2 * bf16tof(v2.z); acc.w += nw2 * bf16tof(v2.w);
            acc.x += nw3 * bf16tof(v3.x); acc.y += nw3 * bf16tof(v3.y);
            acc.z += nw3 * bf16tof(v3.z); acc.w += nw3 * bf16tof(v3.w);
        }
        for (; e < end; ++e) {
            int2 p = pairs[e];
            float nw = dinv[p.x] * __int_as_float(p.y);
            ushort4 v = xh4[p.x * 32 + lane];
            acc.x += nw * bf16tof(v.x); acc.y += nw * bf16tof(v.y);
            acc.z += nw * bf16tof(v.z); acc.w += nw * bf16tof(v.w);
        }
        acc.x *= dn; acc.y *= dn; acc.z *= dn; acc.w *= dn;

        uint2 r;
        r.x = bf16rn(acc.x) | (bf16rn(acc.y) << 16);
        r.y = bf16rn(acc.z) | (bf16rn(acc.w) << 16);
        // swizzled store: col block of 4 stays contiguous (XOR with multiple of 8)
        *(uint2*)&gt[grp][(lane * 4) ^ ((grp & 7) << 3)] = r;
    }
    __syncthreads();

    const int wv   = t >> 6;          // wave 0..7
    const int lane = t & 63;
    const int r16  = lane & 15;
    const int g    = lane >> 4;
    const int swr  = (r16 & 7) << 3;

    // ---- phase B: layer 1, wave wv -> h cols wv*16 .. +15 ----
    {
        bf16x8 a[4];
        #pragma unroll
        for (int kt = 0; kt < 4; ++kt)
            a[kt] = *(const bf16x8*)&gt[r16][(kt * 32 + g * 8) ^ swr];

        f32x4 acc = {0.f, 0.f, 0.f, 0.f};
        const unsigned short* bcol = w1t + (wv * 16 + r16) * HID + g * 8;
        #pragma unroll
        for (int kt = 0; kt < 4; ++kt) {
            bf16x8 b = *(const bf16x8*)(bcol + kt * 32);
            acc = __builtin_amdgcn_mfma_f32_16x16x32_bf16(a[kt], b, acc, 0, 0, 0);
        }
        float bias = b1[wv * 16 + r16];
        #pragma unroll
        for (int q = 0; q < 4; ++q) {
            int row = g * 4 + q;
            float v = fmaxf(acc[q] + bias, 0.0f);
            ht[row][(wv * 16 + r16) ^ ((row & 7) << 3)] = (unsigned short)bf16rn(v);
        }
    }
    __syncthreads();

    // ---- phase C: layer 2, waves 0..3 -> out cols wv*16 .. +15 ----
    if (wv < 4) {
        bf16x8 a2[4];
        #pragma unroll
        for (int kt = 0; kt < 4; ++kt)
            a2[kt] = *(const bf16x8*)&ht[r16][(kt * 32 + g * 8) ^ swr];

        f32x4 acc = {0.f, 0.f, 0.f, 0.f};
        const unsigned short* bcol = w2t + (wv * 16 + r16) * HID + g * 8;
        #pragma unroll
        for (int kt = 0; kt < 4; ++kt) {
            bf16x8 b = *(const bf16x8*)(bcol + kt * 32);
            acc = __builtin_amdgcn_mfma_f32_16x16x32_bf16(a2[kt], b, acc, 0, 0, 0);
        }
        float bias = b2[wv * 16 + r16];
        #pragma unroll
        for (int q = 0; q < 4; ++q)
            out[(size_t)(row0 + g * 4 + q) * F_OUT + wv * 16 + r16] = acc[q] + bias;
    }
}

// ---------------- launch ----------------

extern "C" void kernel_launch(void* const* d_in, const int* in_sizes, int n_in,
                              void* d_out, int out_size, void* d_ws, size_t ws_size,
                              hipStream_t stream) {
    const float* x  = (const float*)d_in[0];
    const int*   ei = (const int*)d_in[1];
    const float* ew = (const float*)d_in[2];
    const float* W1 = (const float*)d_in[3];
    const float* b1 = (const float*)d_in[4];
    const float* W2 = (const float*)d_in[5];
    const float* b2 = (const float*)d_in[6];
    float* out = (float*)d_out;

    const int* src = ei;
    const int* dst = ei + N_EDGES;

    // workspace layout — explicit 16B-aligned carve-out
    char* base = (char*)d_ws;
    auto alloc16 = [&](size_t bytes) { char* p = base; base += (bytes + 15) & ~(size_t)15; return p; };

    float*          dinv    = (float*)         alloc16(N_NODES * 4);
    unsigned short* xh      = (unsigned short*)alloc16((size_t)N_NODES * F_IN * 2);
    int*            row_ptr = (int*)           alloc16((N_NODES + 1) * 4);
    int*            ghist   = (int*)           alloc16(GHN * 4);
    int*            part    = (int*)           alloc16(256 * 4);
    int2*           pairs   = (int2*)          alloc16((size_t)N_EDGES * 8);
    int2*           spw     = (int2*)          alloc16((size_t)N_EDGES * 8);
    unsigned short* w1t     = (unsigned short*)alloc16(HID * F_IN * 2);
    unsigned short* w2t     = (unsigned short*)alloc16(F_OUT * HID * 2);

    const int GH_BLKS = (GHN + 255) / 256;   // 196

    k_pre<<<XB_BLKS + WC_BLKS + NCHB, 256, 0, stream>>>(x, xh, W1, W2, w1t, w2t, dst, ghist);
    k_scan_part<<<GH_BLKS, 256, 0, stream>>>(ghist, part, GHN);
    k_scan_top<<<1, 512, 0, stream>>>(part, GH_BLKS);
    k_scan_down<<<GH_BLKS, 256, 0, stream>>>(ghist, part, GHN);
    k_bscatter<<<NCHB, 256, 0, stream>>>(src, dst, ew, ghist, spw);
    k_csr<<<NBUCK, 512, 0, stream>>>(spw, ghist, row_ptr, dinv, pairs);
    k_gmlp<<<N_NODES / 16, 512, 0, stream>>>(pairs, row_ptr, dinv, xh, w1t, b1, w2t, b2, out);
}